// Round 9
// baseline (664.187 us; speedup 1.0000x reference)
//
#include <hip/hip_runtime.h>
#include <hip/hip_bf16.h>
#include <stdint.h>

#define D_IN 128
#define D_H 256
#define NLAYERS 5

typedef __bf16 bf16x8 __attribute__((ext_vector_type(8)));
typedef __bf16 bf16x4 __attribute__((ext_vector_type(4)));
typedef float f32x4 __attribute__((ext_vector_type(4)));
typedef unsigned short u16x8 __attribute__((ext_vector_type(8)));

// LDS tile row stride in ushorts: 260 u16 = 520 B = 130 dwords; 130%32==2 so
// 16 consecutive rows at one column cover all 32 banks (measured 0 conflicts).
#define MID_STRIDE 260

__device__ inline unsigned short bfbits(float f) {
  __hip_bfloat16 h = __float2bfloat16(f);
  unsigned short s;
  __builtin_memcpy(&s, &h, 2);
  return s;
}

__device__ inline unsigned packbf(float lo, float hi) {
  return (unsigned)bfbits(lo) | ((unsigned)bfbits(hi) << 16);
}

// u holds 2 bf16 (lo in bits 0..15). Accumulate both into a,b.
__device__ inline void addbf2(float& a, float& b, unsigned u) {
  a += __uint_as_float(u << 16);
  b += __uint_as_float(u & 0xffff0000u);
}

__device__ inline void addbf2s(float& a, float& b, unsigned u, float s) {
  a += s * __uint_as_float(u << 16);
  b += s * __uint_as_float(u & 0xffff0000u);
}

// cast x (nx floats) and the 4 weight tensors to bf16, one launch
__global__ void conv_inputs(const float* __restrict__ x, const float* __restrict__ a,
                            const float* __restrict__ b, const float* __restrict__ c,
                            const float* __restrict__ d,
                            __hip_bfloat16* __restrict__ xb,
                            __hip_bfloat16* __restrict__ wb, int nx) {
  int gid = blockIdx.x * blockDim.x + threadIdx.x;
  if (gid < nx) {
    xb[gid] = __float2bfloat16(x[gid]);
    return;
  }
  gid -= nx;
  if (gid >= 622592) return;
  float v;
  if (gid < 32768) v = a[gid];
  else if (gid < 98304) v = b[gid - 32768];
  else if (gid < 360448) v = c[gid - 98304];
  else v = d[gid - 360448];
  wb[gid] = __float2bfloat16(v);
}

__global__ void zero_ints(int* __restrict__ p, int n) {
  int i = blockIdx.x * blockDim.x + threadIdx.x;
  if (i < n) p[i] = 0;
}

// ---- CSR build ----
__global__ void hist_kernel(const int* __restrict__ ei, int E, int* __restrict__ deg) {
  int e = blockIdx.x * blockDim.x + threadIdx.x;
  if (e < E) atomicAdd(&deg[ei[E + e]], 1);
}

__global__ __launch_bounds__(256) void block_sums(const int* __restrict__ deg,
                                                  int* __restrict__ bsum, int N) {
  int t = threadIdx.x;
  int idx = blockIdx.x * 1024 + t * 4;
  int4 v = {0, 0, 0, 0};
  if (idx + 3 < N) v = *reinterpret_cast<const int4*>(deg + idx);
  else {
    if (idx + 0 < N) v.x = deg[idx + 0];
    if (idx + 1 < N) v.y = deg[idx + 1];
    if (idx + 2 < N) v.z = deg[idx + 2];
    if (idx + 3 < N) v.w = deg[idx + 3];
  }
  int s = v.x + v.y + v.z + v.w;
#pragma unroll
  for (int off = 32; off > 0; off >>= 1) s += __shfl_down(s, off);
  __shared__ int ws[4];
  int lane = t & 63, w = t >> 6;
  if (lane == 0) ws[w] = s;
  __syncthreads();
  if (t == 0) bsum[blockIdx.x] = ws[0] + ws[1] + ws[2] + ws[3];
}

__global__ void scan_bsums(int* __restrict__ bsum, int nb) {
  int t = threadIdx.x;
  int orig = (t < nb) ? bsum[t] : 0;
  int v = orig;
#pragma unroll
  for (int off = 1; off < 64; off <<= 1) {
    int u = __shfl_up(v, off);
    if (t >= off) v += u;
  }
  if (t < nb) bsum[t] = v - orig;  // exclusive
}

__global__ __launch_bounds__(256) void scan_apply(const int* __restrict__ deg,
                                                  const int* __restrict__ bsum_ex,
                                                  int* __restrict__ row_start, int N) {
  int t = threadIdx.x;
  int idx = blockIdx.x * 1024 + t * 4;
  int4 v = {0, 0, 0, 0};
  if (idx + 3 < N) v = *reinterpret_cast<const int4*>(deg + idx);
  else {
    if (idx + 0 < N) v.x = deg[idx + 0];
    if (idx + 1 < N) v.y = deg[idx + 1];
    if (idx + 2 < N) v.z = deg[idx + 2];
    if (idx + 3 < N) v.w = deg[idx + 3];
  }
  int s = v.x + v.y + v.z + v.w;
  int lane = t & 63, w = t >> 6;
  int sc = s;
#pragma unroll
  for (int off = 1; off < 64; off <<= 1) {
    int u = __shfl_up(sc, off);
    if (lane >= off) sc += u;
  }
  __shared__ int woff[4];
  if (lane == 63) woff[w] = sc;
  __syncthreads();
  int boff = bsum_ex[blockIdx.x];
#pragma unroll
  for (int i = 0; i < 4; ++i)
    if (i < w) boff += woff[i];
  int ex = boff + sc - s;
  if (idx + 3 < N) {
    int4 o;
    o.x = ex;
    o.y = ex + v.x;
    o.z = ex + v.x + v.y;
    o.w = ex + v.x + v.y + v.z;
    *reinterpret_cast<int4*>(row_start + idx) = o;
  } else {
    if (idx + 0 < N) row_start[idx + 0] = ex;
    if (idx + 1 < N) row_start[idx + 1] = ex + v.x;
    if (idx + 2 < N) row_start[idx + 2] = ex + v.x + v.y;
    if (idx + 3 < N) row_start[idx + 3] = ex + v.x + v.y + v.z;
  }
}

__global__ void fill_kernel(const int* __restrict__ ei, int E,
                            const int* __restrict__ row_start,
                            int* __restrict__ cursor, int* __restrict__ csr) {
  int e = blockIdx.x * blockDim.x + threadIdx.x;
  if (e >= E) return;
  int d = ei[E + e];
  int p = atomicAdd(&cursor[d], 1);
  csr[row_start[d] + p] = ei[e];
}

// ---- aggregation: pre[n] = bf16( (1+eps)*h[n] + sum_{s in in(n)} h[s] ) ----
// All-bf16 input. Half-wave (32 lanes) per node; lane holds D/32 ushorts.
// Indices preloaded 32-at-a-time, broadcast via shfl; 8 rows in flight.
template <int D>  // ushorts per row: 128 (8B/lane) or 256 (16B/lane)
__global__ __launch_bounds__(256) void aggregate(const unsigned short* __restrict__ hb,
                                                 const int* __restrict__ csr,
                                                 const int* __restrict__ row_start,
                                                 const int* __restrict__ deg,
                                                 const float* __restrict__ eps_all,
                                                 int layer,
                                                 unsigned short* __restrict__ pre,
                                                 int N) {
  constexpr int PL = D / 32;  // ushorts per lane: 4 or 8
  const int half = threadIdx.x >> 5;
  const int lane = threadIdx.x & 31;
  const int node = blockIdx.x * 8 + half;
  if (node >= N) return;

  const int start = row_start[node];
  const int cnt = deg[node];
  const float epsv = 1.0f + eps_all[layer];

  float acc[PL];
#pragma unroll
  for (int j = 0; j < PL; ++j) acc[j] = 0.0f;

  if (D == 256) {
    const uint4* base_p = (const uint4*)hb;
    uint4 su = *reinterpret_cast<const uint4*>(hb + (size_t)node * D + lane * 8);
    for (int base = 0; base < cnt; base += 32) {
      int m = cnt - base;
      if (m > 32) m = 32;
      int idx = (lane < m) ? csr[start + base + lane] : 0;
      int i = 0;
      for (; i + 8 <= m; i += 8) {
        uint4 q[8];
#pragma unroll
        for (int r = 0; r < 8; ++r) {
          int s = __shfl(idx, i + r, 32);
          q[r] = *reinterpret_cast<const uint4*>(hb + (size_t)s * D + lane * 8);
        }
#pragma unroll
        for (int r = 0; r < 8; ++r) {
          addbf2(acc[0], acc[1], q[r].x);
          addbf2(acc[2], acc[3], q[r].y);
          addbf2(acc[4], acc[5], q[r].z);
          addbf2(acc[6], acc[7], q[r].w);
        }
      }
      for (; i + 4 <= m; i += 4) {
        uint4 q[4];
#pragma unroll
        for (int r = 0; r < 4; ++r) {
          int s = __shfl(idx, i + r, 32);
          q[r] = *reinterpret_cast<const uint4*>(hb + (size_t)s * D + lane * 8);
        }
#pragma unroll
        for (int r = 0; r < 4; ++r) {
          addbf2(acc[0], acc[1], q[r].x);
          addbf2(acc[2], acc[3], q[r].y);
          addbf2(acc[4], acc[5], q[r].z);
          addbf2(acc[6], acc[7], q[r].w);
        }
      }
      for (; i < m; ++i) {
        int s = __shfl(idx, i, 32);
        uint4 q = *reinterpret_cast<const uint4*>(hb + (size_t)s * D + lane * 8);
        addbf2(acc[0], acc[1], q.x);
        addbf2(acc[2], acc[3], q.y);
        addbf2(acc[4], acc[5], q.z);
        addbf2(acc[6], acc[7], q.w);
      }
    }
    addbf2s(acc[0], acc[1], su.x, epsv);
    addbf2s(acc[2], acc[3], su.y, epsv);
    addbf2s(acc[4], acc[5], su.z, epsv);
    addbf2s(acc[6], acc[7], su.w, epsv);
    uint4 o;
    o.x = packbf(acc[0], acc[1]);
    o.y = packbf(acc[2], acc[3]);
    o.z = packbf(acc[4], acc[5]);
    o.w = packbf(acc[6], acc[7]);
    *reinterpret_cast<uint4*>(pre + (size_t)node * D + lane * 8) = o;
  } else {  // D == 128
    uint2 su = *reinterpret_cast<const uint2*>(hb + (size_t)node * D + lane * 4);
    for (int base = 0; base < cnt; base += 32) {
      int m = cnt - base;
      if (m > 32) m = 32;
      int idx = (lane < m) ? csr[start + base + lane] : 0;
      int i = 0;
      for (; i + 8 <= m; i += 8) {
        uint2 q[8];
#pragma unroll
        for (int r = 0; r < 8; ++r) {
          int s = __shfl(idx, i + r, 32);
          q[r] = *reinterpret_cast<const uint2*>(hb + (size_t)s * D + lane * 4);
        }
#pragma unroll
        for (int r = 0; r < 8; ++r) {
          addbf2(acc[0], acc[1], q[r].x);
          addbf2(acc[2], acc[3], q[r].y);
        }
      }
      for (; i + 4 <= m; i += 4) {
        uint2 q[4];
#pragma unroll
        for (int r = 0; r < 4; ++r) {
          int s = __shfl(idx, i + r, 32);
          q[r] = *reinterpret_cast<const uint2*>(hb + (size_t)s * D + lane * 4);
        }
#pragma unroll
        for (int r = 0; r < 4; ++r) {
          addbf2(acc[0], acc[1], q[r].x);
          addbf2(acc[2], acc[3], q[r].y);
        }
      }
      for (; i < m; ++i) {
        int s = __shfl(idx, i, 32);
        uint2 q = *reinterpret_cast<const uint2*>(hb + (size_t)s * D + lane * 4);
        addbf2(acc[0], acc[1], q.x);
        addbf2(acc[2], acc[3], q.y);
      }
    }
    addbf2s(acc[0], acc[1], su.x, epsv);
    addbf2s(acc[2], acc[3], su.y, epsv);
    uint2 o;
    o.x = packbf(acc[0], acc[1]);
    o.y = packbf(acc[2], acc[3]);
    *reinterpret_cast<uint2*>(pre + (size_t)node * D + lane * 4) = o;
  }
}

// ---- fused 2-layer MLP: out = relu( relu(A@W0.T+b0) @ W1.T + b1 ) ----
// Block = 256 thr (4 waves) = 32 rows x 256 cols; grid = N/32 = 1563 blocks
// (~6 blocks/CU resident -> phase barriers of one block hide under others).
// Phase 0: stage 32xK0 A-tile into LDS (coalesced 16B/thread).
// Phase 1: GEMM0 from LDS (8 MFMA : 4 W-b128 : 4 ds-b64 per k-step).
// Phase 2: epilogue0 overwrites LDS tile with mid = relu(.+b0).
// Phase 3: GEMM1 from LDS -> global.
// mfma_f32_16x16x32_bf16 frag maps: A/B row/col = lane&15, k = (lane>>4)*8 + j;
// C/D: col = lane&15, row = (lane>>4)*4 + reg.
template <int K0, bool OUT_BF16>
__global__ __launch_bounds__(256) void gin_mlp(const __hip_bfloat16* __restrict__ Ap,
                                               const __hip_bfloat16* __restrict__ W0,
                                               const float* __restrict__ b0,
                                               const __hip_bfloat16* __restrict__ W1,
                                               const float* __restrict__ b1,
                                               void* __restrict__ Outp, int Nrows) {
  __shared__ unsigned short Abuf[32 * MID_STRIDE];  // 16.6 KB; A-tile then mid

  const int row0 = blockIdx.x * 32;

  // ---- Phase 0: stage A-tile into LDS ----
  {
    constexpr int CPR = K0 / 8;  // 16B chunks per row
    constexpr int TOT = 32 * CPR;
    const unsigned short* As = (const unsigned short*)Ap;
#pragma unroll
    for (int c = threadIdx.x; c < TOT; c += 256) {
      int row = c / CPR;
      int col = (c % CPR) * 8;
      int grow = row0 + row;
      if (grow > Nrows - 1) grow = Nrows - 1;  // clamp: dup rows feed discarded C
      u16x8 v = *reinterpret_cast<const u16x8*>(As + (size_t)grow * K0 + col);
      *reinterpret_cast<u16x8*>(Abuf + row * MID_STRIDE + col) = v;
    }
  }
  __syncthreads();

  const int lane = threadIdx.x & 63;
  const int wave = threadIdx.x >> 6;  // 0..3
  const int l15 = lane & 15;
  const int kg = lane >> 4;  // 0..3
  const int col0 = wave * 64;

  // ---- Phase 1: GEMM0 (A from LDS, W from L2) ----
  const __hip_bfloat16* w0row[4];
#pragma unroll
  for (int ct = 0; ct < 4; ++ct)
    w0row[ct] = W0 + (size_t)(col0 + ct * 16 + l15) * K0 + kg * 8;

  f32x4 acc0[2][4];
#pragma unroll
  for (int rt = 0; rt < 2; ++rt)
#pragma unroll
    for (int ct = 0; ct < 4; ++ct) acc0[rt][ct] = 0.0f;

#pragma unroll
  for (int kk = 0; kk < K0 / 32; ++kk) {
    const int off = kk * 32;
    bf16x8 bfr[4];
#pragma unroll
    for (int ct = 0; ct < 4; ++ct)
      bfr[ct] = *reinterpret_cast<const bf16x8*>(w0row[ct] + off);
    bf16x8 afr[2];
#pragma unroll
    for (int rt = 0; rt < 2; ++rt) {
      const unsigned short* p = Abuf + (rt * 16 + l15) * MID_STRIDE + off + kg * 8;
      bf16x4 lo = *reinterpret_cast<const bf16x4*>(p);
      bf16x4 hi = *reinterpret_cast<const bf16x4*>(p + 4);
      bf16x8 a;
#pragma unroll
      for (int j = 0; j < 4; ++j) {
        a[j] = lo[j];
        a[j + 4] = hi[j];
      }
      afr[rt] = a;
    }
#pragma unroll
    for (int rt = 0; rt < 2; ++rt)
#pragma unroll
      for (int ct = 0; ct < 4; ++ct)
        acc0[rt][ct] = __builtin_amdgcn_mfma_f32_16x16x32_bf16(afr[rt], bfr[ct],
                                                               acc0[rt][ct], 0, 0, 0);
  }
  __syncthreads();  // all reads of Abuf done before overwrite

  // ---- Phase 2: epilogue0 -> LDS (mid = relu(. + b0), bf16) ----
#pragma unroll
  for (int ct = 0; ct < 4; ++ct) {
    int col = col0 + ct * 16 + l15;
    float bv = b0[col];
#pragma unroll
    for (int rt = 0; rt < 2; ++rt)
#pragma unroll
      for (int i = 0; i < 4; ++i) {
        int row_l = rt * 16 + kg * 4 + i;
        Abuf[row_l * MID_STRIDE + col] = bfbits(fmaxf(acc0[rt][ct][i] + bv, 0.0f));
      }
  }
  __syncthreads();

  // ---- Phase 3: GEMM1 (A from LDS, K=256) ----
  const unsigned short* w1row[4];
#pragma unroll
  for (int ct = 0; ct < 4; ++ct)
    w1row[ct] =
        (const unsigned short*)W1 + (size_t)(col0 + ct * 16 + l15) * D_H + kg * 8;

  f32x4 acc1[2][4];
#pragma unroll
  for (int rt = 0; rt < 2; ++rt)
#pragma unroll
    for (int ct = 0; ct < 4; ++ct) acc1[rt][ct] = 0.0f;

#pragma unroll
  for (int kk = 0; kk < D_H / 32; ++kk) {
    const int off = kk * 32;
    bf16x8 wfr[4];
#pragma unroll
    for (int ct = 0; ct < 4; ++ct)
      wfr[ct] = *reinterpret_cast<const bf16x8*>(w1row[ct] + off);
    bf16x8 afr[2];
#pragma unroll
    for (int rt = 0; rt < 2; ++rt) {
      const unsigned short* p = Abuf + (rt * 16 + l15) * MID_STRIDE + off + kg * 8;
      bf16x4 lo = *reinterpret_cast<const bf16x4*>(p);
      bf16x4 hi = *reinterpret_cast<const bf16x4*>(p + 4);
      bf16x8 a;
#pragma unroll
      for (int j = 0; j < 4; ++j) {
        a[j] = lo[j];
        a[j + 4] = hi[j];
      }
      afr[rt] = a;
    }
#pragma unroll
    for (int rt = 0; rt < 2; ++rt)
#pragma unroll
      for (int ct = 0; ct < 4; ++ct)
        acc1[rt][ct] = __builtin_amdgcn_mfma_f32_16x16x32_bf16(afr[rt], wfr[ct],
                                                               acc1[rt][ct], 0, 0, 0);
  }

  // ---- epilogue1 -> global (relu) ----
#pragma unroll
  for (int ct = 0; ct < 4; ++ct) {
    int col = col0 + ct * 16 + l15;
    float bv = b1[col];
#pragma unroll
    for (int rt = 0; rt < 2; ++rt)
#pragma unroll
      for (int i = 0; i < 4; ++i) {
        int row = row0 + rt * 16 + kg * 4 + i;
        if (row < Nrows) {
          float v = fmaxf(acc1[rt][ct][i] + bv, 0.0f);
          if (OUT_BF16)
            ((__hip_bfloat16*)Outp)[(size_t)row * D_H + col] = __float2bfloat16(v);
          else
            ((float*)Outp)[(size_t)row * D_H + col] = v;
        }
      }
  }
}

extern "C" void kernel_launch(void* const* d_in, const int* in_sizes, int n_in,
                              void* d_out, int out_size, void* d_ws, size_t ws_size,
                              hipStream_t stream) {
  const float* x = (const float*)d_in[0];
  const int* ei = (const int*)d_in[1];  // [2, E]: row0 = src, row1 = dst
  const float* eps_all = (const float*)d_in[2];
  const float* w0_l0 = (const float*)d_in[3];
  const float* b0_l0 = (const float*)d_in[4];
  const float* w1_l0 = (const float*)d_in[5];
  const float* b1_l0 = (const float*)d_in[6];
  const float* w0_rest = (const float*)d_in[7];
  const float* b0_rest = (const float*)d_in[8];
  const float* w1_rest = (const float*)d_in[9];
  const float* b1_rest = (const float*)d_in[10];

  const int N = in_sizes[0] / D_IN;  // 50000
  const int E = in_sizes[1] / 2;     // 800000
  const int NX = N * D_IN;           // x elements

  char* ws = (char*)d_ws;
  const size_t node_bf = (size_t)N * D_H * sizeof(unsigned short);  // 25.6 MB
  unsigned short* h = (unsigned short*)ws;  // layer outputs (bf16)
  unsigned short* pre = (unsigned short*)(ws + node_bf);
  unsigned short* xb = (unsigned short*)(ws + 2 * node_bf);  // x cast to bf16
  char* p = ws + 2 * node_bf + (size_t)NX * sizeof(unsigned short);
  __hip_bfloat16* wbf = (__hip_bfloat16*)p;
  p += 622592 * sizeof(__hip_bfloat16);
  int* deg = (int*)p;           // [N]
  int* cursor = deg + N;        // [N]
  int* row_start = cursor + N;  // [N]
  int* bsum = row_start + N;    // [64]
  int* csr = bsum + 64;         // [E]

  __hip_bfloat16* w0_l0_bf = wbf;
  __hip_bfloat16* w1_l0_bf = wbf + 32768;
  __hip_bfloat16* w0_rest_bf = wbf + 98304;
  __hip_bfloat16* w1_rest_bf = w0_rest_bf + 262144;

  conv_inputs<<<(NX + 622592 + 255) / 256, 256, 0, stream>>>(
      x, w0_l0, w1_l0, w0_rest, w1_rest, (__hip_bfloat16*)xb, wbf, NX);

  // CSR build
  const int nb = (N + 1023) / 1024;  // 49
  zero_ints<<<(2 * N + 255) / 256, 256, 0, stream>>>(deg, 2 * N);  // deg + cursor
  hist_kernel<<<(E + 255) / 256, 256, 0, stream>>>(ei, E, deg);
  block_sums<<<nb, 256, 0, stream>>>(deg, bsum, N);
  scan_bsums<<<1, 64, 0, stream>>>(bsum, nb);
  scan_apply<<<nb, 256, 0, stream>>>(deg, bsum, row_start, N);
  fill_kernel<<<(E + 255) / 256, 256, 0, stream>>>(ei, E, row_start, cursor, csr);

  const int gemmBlocks = (N + 31) / 32;
  const int aggBlocks = (N + 7) / 8;

  for (int layer = 0; layer < NLAYERS; ++layer) {
    const __hip_bfloat16* w0 =
        (layer == 0) ? w0_l0_bf : w0_rest_bf + (size_t)(layer - 1) * 65536;
    const float* b0 = (layer == 0) ? b0_l0 : b0_rest + (size_t)(layer - 1) * 256;
    const __hip_bfloat16* w1 =
        (layer == 0) ? w1_l0_bf : w1_rest_bf + (size_t)(layer - 1) * 65536;
    const float* b1 = (layer == 0) ? b1_l0 : b1_rest + (size_t)(layer - 1) * 256;

    if (layer == 0) {
      aggregate<D_IN><<<aggBlocks, 256, 0, stream>>>(xb, csr, row_start, deg,
                                                     eps_all, layer, pre, N);
      gin_mlp<D_IN, true><<<gemmBlocks, 256, 0, stream>>>(
          (const __hip_bfloat16*)pre, w0, b0, w1, b1, h, N);
    } else {
      aggregate<D_H><<<aggBlocks, 256, 0, stream>>>(h, csr, row_start, deg,
                                                    eps_all, layer, pre, N);
      if (layer == NLAYERS - 1)
        gin_mlp<D_H, false><<<gemmBlocks, 256, 0, stream>>>(
            (const __hip_bfloat16*)pre, w0, b0, w1, b1, d_out, N);
      else
        gin_mlp<D_H, true><<<gemmBlocks, 256, 0, stream>>>(
            (const __hip_bfloat16*)pre, w0, b0, w1, b1, h, N);
    }
  }
}

// Round 10
// 609.156 us; speedup vs baseline: 1.0903x; 1.0903x over previous
//
#include <hip/hip_runtime.h>
#include <hip/hip_bf16.h>
#include <stdint.h>

#define D_IN 128
#define D_H 256
#define NLAYERS 5

typedef __bf16 bf16x8 __attribute__((ext_vector_type(8)));
typedef __bf16 bf16x4 __attribute__((ext_vector_type(4)));
typedef float f32x4 __attribute__((ext_vector_type(4)));
typedef unsigned short u16x8 __attribute__((ext_vector_type(8)));

// LDS tile row stride in ushorts: 260 u16 = 520 B = 130 dwords; 130%32==2 so
// 16 consecutive rows at one column cover all 32 banks.
#define MID_STRIDE 260

__device__ inline unsigned short bfbits(float f) {
  __hip_bfloat16 h = __float2bfloat16(f);
  unsigned short s;
  __builtin_memcpy(&s, &h, 2);
  return s;
}

__device__ inline unsigned packbf(float lo, float hi) {
  return (unsigned)bfbits(lo) | ((unsigned)bfbits(hi) << 16);
}

// u holds 2 bf16 (lo in bits 0..15). Accumulate both into a,b.
__device__ inline void addbf2(float& a, float& b, unsigned u) {
  a += __uint_as_float(u << 16);
  b += __uint_as_float(u & 0xffff0000u);
}

__device__ inline void addbf2s(float& a, float& b, unsigned u, float s) {
  a += s * __uint_as_float(u << 16);
  b += s * __uint_as_float(u & 0xffff0000u);
}

// cast x (nx floats) and the 4 weight tensors to bf16, one launch
__global__ void conv_inputs(const float* __restrict__ x, const float* __restrict__ a,
                            const float* __restrict__ b, const float* __restrict__ c,
                            const float* __restrict__ d,
                            __hip_bfloat16* __restrict__ xb,
                            __hip_bfloat16* __restrict__ wb, int nx) {
  int gid = blockIdx.x * blockDim.x + threadIdx.x;
  if (gid < nx) {
    xb[gid] = __float2bfloat16(x[gid]);
    return;
  }
  gid -= nx;
  if (gid >= 622592) return;
  float v;
  if (gid < 32768) v = a[gid];
  else if (gid < 98304) v = b[gid - 32768];
  else if (gid < 360448) v = c[gid - 98304];
  else v = d[gid - 360448];
  wb[gid] = __float2bfloat16(v);
}

__global__ void zero_ints(int* __restrict__ p, int n) {
  int i = blockIdx.x * blockDim.x + threadIdx.x;
  if (i < n) p[i] = 0;
}

// ---- CSR build ----
__global__ void hist_kernel(const int* __restrict__ ei, int E, int* __restrict__ deg) {
  int e = blockIdx.x * blockDim.x + threadIdx.x;
  if (e < E) atomicAdd(&deg[ei[E + e]], 1);
}

__global__ __launch_bounds__(256) void block_sums(const int* __restrict__ deg,
                                                  int* __restrict__ bsum, int N) {
  int t = threadIdx.x;
  int idx = blockIdx.x * 1024 + t * 4;
  int4 v = {0, 0, 0, 0};
  if (idx + 3 < N) v = *reinterpret_cast<const int4*>(deg + idx);
  else {
    if (idx + 0 < N) v.x = deg[idx + 0];
    if (idx + 1 < N) v.y = deg[idx + 1];
    if (idx + 2 < N) v.z = deg[idx + 2];
    if (idx + 3 < N) v.w = deg[idx + 3];
  }
  int s = v.x + v.y + v.z + v.w;
#pragma unroll
  for (int off = 32; off > 0; off >>= 1) s += __shfl_down(s, off);
  __shared__ int ws[4];
  int lane = t & 63, w = t >> 6;
  if (lane == 0) ws[w] = s;
  __syncthreads();
  if (t == 0) bsum[blockIdx.x] = ws[0] + ws[1] + ws[2] + ws[3];
}

__global__ void scan_bsums(int* __restrict__ bsum, int nb) {
  int t = threadIdx.x;
  int orig = (t < nb) ? bsum[t] : 0;
  int v = orig;
#pragma unroll
  for (int off = 1; off < 64; off <<= 1) {
    int u = __shfl_up(v, off);
    if (t >= off) v += u;
  }
  if (t < nb) bsum[t] = v - orig;  // exclusive
}

__global__ __launch_bounds__(256) void scan_apply(const int* __restrict__ deg,
                                                  const int* __restrict__ bsum_ex,
                                                  int* __restrict__ row_start, int N) {
  int t = threadIdx.x;
  int idx = blockIdx.x * 1024 + t * 4;
  int4 v = {0, 0, 0, 0};
  if (idx + 3 < N) v = *reinterpret_cast<const int4*>(deg + idx);
  else {
    if (idx + 0 < N) v.x = deg[idx + 0];
    if (idx + 1 < N) v.y = deg[idx + 1];
    if (idx + 2 < N) v.z = deg[idx + 2];
    if (idx + 3 < N) v.w = deg[idx + 3];
  }
  int s = v.x + v.y + v.z + v.w;
  int lane = t & 63, w = t >> 6;
  int sc = s;
#pragma unroll
  for (int off = 1; off < 64; off <<= 1) {
    int u = __shfl_up(sc, off);
    if (lane >= off) sc += u;
  }
  __shared__ int woff[4];
  if (lane == 63) woff[w] = sc;
  __syncthreads();
  int boff = bsum_ex[blockIdx.x];
#pragma unroll
  for (int i = 0; i < 4; ++i)
    if (i < w) boff += woff[i];
  int ex = boff + sc - s;
  if (idx + 3 < N) {
    int4 o;
    o.x = ex;
    o.y = ex + v.x;
    o.z = ex + v.x + v.y;
    o.w = ex + v.x + v.y + v.z;
    *reinterpret_cast<int4*>(row_start + idx) = o;
  } else {
    if (idx + 0 < N) row_start[idx + 0] = ex;
    if (idx + 1 < N) row_start[idx + 1] = ex + v.x;
    if (idx + 2 < N) row_start[idx + 2] = ex + v.x + v.y;
    if (idx + 3 < N) row_start[idx + 3] = ex + v.x + v.y + v.z;
  }
}

__global__ void fill_kernel(const int* __restrict__ ei, int E,
                            const int* __restrict__ row_start,
                            int* __restrict__ cursor, int* __restrict__ csr) {
  int e = blockIdx.x * blockDim.x + threadIdx.x;
  if (e >= E) return;
  int d = ei[E + e];
  int p = atomicAdd(&cursor[d], 1);
  csr[row_start[d] + p] = ei[e];
}

// ---- aggregation: pre[n] = bf16( (1+eps)*h[n] + sum_{s in in(n)} h[s] ) ----
// All-bf16 input. Half-wave (32 lanes) per node; indices broadcast via shfl;
// 8 rows in flight.
template <int D>
__global__ __launch_bounds__(256) void aggregate(const unsigned short* __restrict__ hb,
                                                 const int* __restrict__ csr,
                                                 const int* __restrict__ row_start,
                                                 const int* __restrict__ deg,
                                                 const float* __restrict__ eps_all,
                                                 int layer,
                                                 unsigned short* __restrict__ pre,
                                                 int N) {
  constexpr int PL = D / 32;  // ushorts per lane: 4 or 8
  const int half = threadIdx.x >> 5;
  const int lane = threadIdx.x & 31;
  const int node = blockIdx.x * 8 + half;
  if (node >= N) return;

  const int start = row_start[node];
  const int cnt = deg[node];
  const float epsv = 1.0f + eps_all[layer];

  float acc[PL];
#pragma unroll
  for (int j = 0; j < PL; ++j) acc[j] = 0.0f;

  if (D == 256) {
    uint4 su = *reinterpret_cast<const uint4*>(hb + (size_t)node * D + lane * 8);
    for (int base = 0; base < cnt; base += 32) {
      int m = cnt - base;
      if (m > 32) m = 32;
      int idx = (lane < m) ? csr[start + base + lane] : 0;
      int i = 0;
      for (; i + 8 <= m; i += 8) {
        uint4 q[8];
#pragma unroll
        for (int r = 0; r < 8; ++r) {
          int s = __shfl(idx, i + r, 32);
          q[r] = *reinterpret_cast<const uint4*>(hb + (size_t)s * D + lane * 8);
        }
#pragma unroll
        for (int r = 0; r < 8; ++r) {
          addbf2(acc[0], acc[1], q[r].x);
          addbf2(acc[2], acc[3], q[r].y);
          addbf2(acc[4], acc[5], q[r].z);
          addbf2(acc[6], acc[7], q[r].w);
        }
      }
      for (; i + 4 <= m; i += 4) {
        uint4 q[4];
#pragma unroll
        for (int r = 0; r < 4; ++r) {
          int s = __shfl(idx, i + r, 32);
          q[r] = *reinterpret_cast<const uint4*>(hb + (size_t)s * D + lane * 8);
        }
#pragma unroll
        for (int r = 0; r < 4; ++r) {
          addbf2(acc[0], acc[1], q[r].x);
          addbf2(acc[2], acc[3], q[r].y);
          addbf2(acc[4], acc[5], q[r].z);
          addbf2(acc[6], acc[7], q[r].w);
        }
      }
      for (; i < m; ++i) {
        int s = __shfl(idx, i, 32);
        uint4 q = *reinterpret_cast<const uint4*>(hb + (size_t)s * D + lane * 8);
        addbf2(acc[0], acc[1], q.x);
        addbf2(acc[2], acc[3], q.y);
        addbf2(acc[4], acc[5], q.z);
        addbf2(acc[6], acc[7], q.w);
      }
    }
    addbf2s(acc[0], acc[1], su.x, epsv);
    addbf2s(acc[2], acc[3], su.y, epsv);
    addbf2s(acc[4], acc[5], su.z, epsv);
    addbf2s(acc[6], acc[7], su.w, epsv);
    uint4 o;
    o.x = packbf(acc[0], acc[1]);
    o.y = packbf(acc[2], acc[3]);
    o.z = packbf(acc[4], acc[5]);
    o.w = packbf(acc[6], acc[7]);
    *reinterpret_cast<uint4*>(pre + (size_t)node * D + lane * 8) = o;
  } else {  // D == 128
    uint2 su = *reinterpret_cast<const uint2*>(hb + (size_t)node * D + lane * 4);
    for (int base = 0; base < cnt; base += 32) {
      int m = cnt - base;
      if (m > 32) m = 32;
      int idx = (lane < m) ? csr[start + base + lane] : 0;
      int i = 0;
      for (; i + 8 <= m; i += 8) {
        uint2 q[8];
#pragma unroll
        for (int r = 0; r < 8; ++r) {
          int s = __shfl(idx, i + r, 32);
          q[r] = *reinterpret_cast<const uint2*>(hb + (size_t)s * D + lane * 4);
        }
#pragma unroll
        for (int r = 0; r < 8; ++r) {
          addbf2(acc[0], acc[1], q[r].x);
          addbf2(acc[2], acc[3], q[r].y);
        }
      }
      for (; i + 4 <= m; i += 4) {
        uint2 q[4];
#pragma unroll
        for (int r = 0; r < 4; ++r) {
          int s = __shfl(idx, i + r, 32);
          q[r] = *reinterpret_cast<const uint2*>(hb + (size_t)s * D + lane * 4);
        }
#pragma unroll
        for (int r = 0; r < 4; ++r) {
          addbf2(acc[0], acc[1], q[r].x);
          addbf2(acc[2], acc[3], q[r].y);
        }
      }
      for (; i < m; ++i) {
        int s = __shfl(idx, i, 32);
        uint2 q = *reinterpret_cast<const uint2*>(hb + (size_t)s * D + lane * 4);
        addbf2(acc[0], acc[1], q.x);
        addbf2(acc[2], acc[3], q.y);
      }
    }
    addbf2s(acc[0], acc[1], su.x, epsv);
    addbf2s(acc[2], acc[3], su.y, epsv);
    uint2 o;
    o.x = packbf(acc[0], acc[1]);
    o.y = packbf(acc[2], acc[3]);
    *reinterpret_cast<uint2*>(pre + (size_t)node * D + lane * 4) = o;
  }
}

// ---- fused 2-layer MLP: out = relu( relu(A@W0.T+b0) @ W1.T + b1 ) ----
// Block = 256 thr (4 waves) = 64 rows (T=2 tiles) x 256 cols; wave owns 64
// cols for both row-tiles so W-frags amortize over 16 MFMAs per k-step, and
// W-frags for k+1 are PREFETCHED (double-buffered in regs) before MFMAing k.
// Phase 0: stage 64xK0 A-tile into LDS (coalesced 16B/thread).
// Phase 1: GEMM0 from LDS. Phase 2: mid=relu(.+b0) overwrites LDS tile.
// Phase 3: GEMM1 from LDS -> global.
// mfma_f32_16x16x32_bf16 frag maps: A/B row/col = lane&15, k = (lane>>4)*8 + j;
// C/D: col = lane&15, row = (lane>>4)*4 + reg.
template <int K0, bool OUT_BF16>
__global__ __launch_bounds__(256) void gin_mlp(const __hip_bfloat16* __restrict__ Ap,
                                               const __hip_bfloat16* __restrict__ W0,
                                               const float* __restrict__ b0,
                                               const __hip_bfloat16* __restrict__ W1,
                                               const float* __restrict__ b1,
                                               void* __restrict__ Outp, int Nrows) {
  __shared__ unsigned short Abuf[64 * MID_STRIDE];  // 33.3 KB; A-tile then mid

  const int row0 = blockIdx.x * 64;

  // ---- Phase 0: stage A-tile into LDS ----
  {
    constexpr int CPR = K0 / 8;  // 16B chunks per row
    constexpr int TOT = 64 * CPR;
    const unsigned short* As = (const unsigned short*)Ap;
#pragma unroll
    for (int c = threadIdx.x; c < TOT; c += 256) {
      int row = c / CPR;
      int col = (c % CPR) * 8;
      int grow = row0 + row;
      if (grow > Nrows - 1) grow = Nrows - 1;  // clamp: dup rows feed discarded C
      u16x8 v = *reinterpret_cast<const u16x8*>(As + (size_t)grow * K0 + col);
      *reinterpret_cast<u16x8*>(Abuf + row * MID_STRIDE + col) = v;
    }
  }
  __syncthreads();

  const int lane = threadIdx.x & 63;
  const int wave = threadIdx.x >> 6;  // 0..3
  const int l15 = lane & 15;
  const int kg = lane >> 4;  // 0..3
  const int col0 = wave * 64;

  // ---- Phase 1: GEMM0 (A from LDS, W prefetched from L2) ----
  const __hip_bfloat16* w0row[4];
#pragma unroll
  for (int ct = 0; ct < 4; ++ct)
    w0row[ct] = W0 + (size_t)(col0 + ct * 16 + l15) * K0 + kg * 8;

  f32x4 acc0[2][2][4];
#pragma unroll
  for (int t = 0; t < 2; ++t)
#pragma unroll
    for (int rt = 0; rt < 2; ++rt)
#pragma unroll
      for (int ct = 0; ct < 4; ++ct) acc0[t][rt][ct] = 0.0f;

  constexpr int NK0 = K0 / 32;
  {
    bf16x8 bcur[4];
#pragma unroll
    for (int ct = 0; ct < 4; ++ct)
      bcur[ct] = *reinterpret_cast<const bf16x8*>(w0row[ct]);
#pragma unroll
    for (int kk = 0; kk < NK0; ++kk) {
      bf16x8 bnxt[4];
      if (kk + 1 < NK0) {
        const int noff = (kk + 1) * 32;
#pragma unroll
        for (int ct = 0; ct < 4; ++ct)
          bnxt[ct] = *reinterpret_cast<const bf16x8*>(w0row[ct] + noff);
      }
      const int off = kk * 32;
      bf16x8 afr[2][2];
#pragma unroll
      for (int t = 0; t < 2; ++t)
#pragma unroll
        for (int rt = 0; rt < 2; ++rt) {
          const unsigned short* p =
              Abuf + (t * 32 + rt * 16 + l15) * MID_STRIDE + off + kg * 8;
          bf16x4 lo = *reinterpret_cast<const bf16x4*>(p);
          bf16x4 hi = *reinterpret_cast<const bf16x4*>(p + 4);
          bf16x8 a;
#pragma unroll
          for (int j = 0; j < 4; ++j) {
            a[j] = lo[j];
            a[j + 4] = hi[j];
          }
          afr[t][rt] = a;
        }
#pragma unroll
      for (int t = 0; t < 2; ++t)
#pragma unroll
        for (int rt = 0; rt < 2; ++rt)
#pragma unroll
          for (int ct = 0; ct < 4; ++ct)
            acc0[t][rt][ct] = __builtin_amdgcn_mfma_f32_16x16x32_bf16(
                afr[t][rt], bcur[ct], acc0[t][rt][ct], 0, 0, 0);
      if (kk + 1 < NK0) {
#pragma unroll
        for (int ct = 0; ct < 4; ++ct) bcur[ct] = bnxt[ct];
      }
    }
  }
  __syncthreads();  // all reads of Abuf done before overwrite

  // ---- Phase 2: epilogue0 -> LDS (mid = relu(. + b0), bf16) ----
#pragma unroll
  for (int t = 0; t < 2; ++t)
#pragma unroll
    for (int ct = 0; ct < 4; ++ct) {
      int col = col0 + ct * 16 + l15;
      float bv = b0[col];
#pragma unroll
      for (int rt = 0; rt < 2; ++rt)
#pragma unroll
        for (int i = 0; i < 4; ++i) {
          int row_l = t * 32 + rt * 16 + kg * 4 + i;
          Abuf[row_l * MID_STRIDE + col] =
              bfbits(fmaxf(acc0[t][rt][ct][i] + bv, 0.0f));
        }
    }
  __syncthreads();

  // ---- Phase 3: GEMM1 (A from LDS, K=256; W prefetched) ----
  const unsigned short* w1row[4];
#pragma unroll
  for (int ct = 0; ct < 4; ++ct)
    w1row[ct] =
        (const unsigned short*)W1 + (size_t)(col0 + ct * 16 + l15) * D_H + kg * 8;

  f32x4 acc1[2][2][4];
#pragma unroll
  for (int t = 0; t < 2; ++t)
#pragma unroll
    for (int rt = 0; rt < 2; ++rt)
#pragma unroll
      for (int ct = 0; ct < 4; ++ct) acc1[t][rt][ct] = 0.0f;

  constexpr int NK1 = D_H / 32;
  {
    bf16x8 wcur[4];
#pragma unroll
    for (int ct = 0; ct < 4; ++ct)
      wcur[ct] = *reinterpret_cast<const bf16x8*>(w1row[ct]);
#pragma unroll
    for (int kk = 0; kk < NK1; ++kk) {
      bf16x8 wnxt[4];
      if (kk + 1 < NK1) {
        const int noff = (kk + 1) * 32;
#pragma unroll
        for (int ct = 0; ct < 4; ++ct)
          wnxt[ct] = *reinterpret_cast<const bf16x8*>(w1row[ct] + noff);
      }
      const int off = kk * 32;
      bf16x8 afr[2][2];
#pragma unroll
      for (int t = 0; t < 2; ++t)
#pragma unroll
        for (int rt = 0; rt < 2; ++rt) {
          const unsigned short* p =
              Abuf + (t * 32 + rt * 16 + l15) * MID_STRIDE + off + kg * 8;
          bf16x4 lo = *reinterpret_cast<const bf16x4*>(p);
          bf16x4 hi = *reinterpret_cast<const bf16x4*>(p + 4);
          bf16x8 a;
#pragma unroll
          for (int j = 0; j < 4; ++j) {
            a[j] = lo[j];
            a[j + 4] = hi[j];
          }
          afr[t][rt] = a;
        }
#pragma unroll
      for (int t = 0; t < 2; ++t)
#pragma unroll
        for (int rt = 0; rt < 2; ++rt)
#pragma unroll
          for (int ct = 0; ct < 4; ++ct)
            acc1[t][rt][ct] = __builtin_amdgcn_mfma_f32_16x16x32_bf16(
                afr[t][rt], wcur[ct], acc1[t][rt][ct], 0, 0, 0);
      if (kk + 1 < NK1) {
#pragma unroll
        for (int ct = 0; ct < 4; ++ct) wcur[ct] = wnxt[ct];
      }
    }
  }

  // ---- epilogue1 -> global (relu) ----
#pragma unroll
  for (int t = 0; t < 2; ++t)
#pragma unroll
    for (int ct = 0; ct < 4; ++ct) {
      int col = col0 + ct * 16 + l15;
      float bv = b1[col];
#pragma unroll
      for (int rt = 0; rt < 2; ++rt)
#pragma unroll
        for (int i = 0; i < 4; ++i) {
          int row = row0 + t * 32 + rt * 16 + kg * 4 + i;
          if (row < Nrows) {
            float v = fmaxf(acc1[t][rt][ct][i] + bv, 0.0f);
            if (OUT_BF16)
              ((__hip_bfloat16*)Outp)[(size_t)row * D_H + col] = __float2bfloat16(v);
            else
              ((float*)Outp)[(size_t)row * D_H + col] = v;
          }
        }
    }
}

extern "C" void kernel_launch(void* const* d_in, const int* in_sizes, int n_in,
                              void* d_out, int out_size, void* d_ws, size_t ws_size,
                              hipStream_t stream) {
  const float* x = (const float*)d_in[0];
  const int* ei = (const int*)d_in[1];  // [2, E]: row0 = src, row1 = dst
  const float* eps_all = (const float*)d_in[2];
  const float* w0_l0 = (const float*)d_in[3];
  const float* b0_l0 = (const float*)d_in[4];
  const float* w1_l0 = (const float*)d_in[5];
  const float* b1_l0 = (const float*)d_in[6];
  const float* w0_rest = (const float*)d_in[7];
  const float* b0_rest = (const float*)d_in[8];
  const float* w1_rest = (const float*)d_in[9];
  const float* b1_rest = (const float*)d_in[10];

  const int N = in_sizes[0] / D_IN;  // 50000
  const int E = in_sizes[1] / 2;     // 800000
  const int NX = N * D_IN;           // x elements

  char* ws = (char*)d_ws;
  const size_t node_bf = (size_t)N * D_H * sizeof(unsigned short);  // 25.6 MB
  unsigned short* h = (unsigned short*)ws;  // layer outputs (bf16)
  unsigned short* pre = (unsigned short*)(ws + node_bf);
  unsigned short* xb = (unsigned short*)(ws + 2 * node_bf);  // x cast to bf16
  char* p = ws + 2 * node_bf + (size_t)NX * sizeof(unsigned short);
  __hip_bfloat16* wbf = (__hip_bfloat16*)p;
  p += 622592 * sizeof(__hip_bfloat16);
  int* deg = (int*)p;           // [N]
  int* cursor = deg + N;        // [N]
  int* row_start = cursor + N;  // [N]
  int* bsum = row_start + N;    // [64]
  int* csr = bsum + 64;         // [E]

  __hip_bfloat16* w0_l0_bf = wbf;
  __hip_bfloat16* w1_l0_bf = wbf + 32768;
  __hip_bfloat16* w0_rest_bf = wbf + 98304;
  __hip_bfloat16* w1_rest_bf = w0_rest_bf + 262144;

  conv_inputs<<<(NX + 622592 + 255) / 256, 256, 0, stream>>>(
      x, w0_l0, w1_l0, w0_rest, w1_rest, (__hip_bfloat16*)xb, wbf, NX);

  // CSR build
  const int nb = (N + 1023) / 1024;  // 49
  zero_ints<<<(2 * N + 255) / 256, 256, 0, stream>>>(deg, 2 * N);  // deg + cursor
  hist_kernel<<<(E + 255) / 256, 256, 0, stream>>>(ei, E, deg);
  block_sums<<<nb, 256, 0, stream>>>(deg, bsum, N);
  scan_bsums<<<1, 64, 0, stream>>>(bsum, nb);
  scan_apply<<<nb, 256, 0, stream>>>(deg, bsum, row_start, N);
  fill_kernel<<<(E + 255) / 256, 256, 0, stream>>>(ei, E, row_start, cursor, csr);

  const int gemmBlocks = (N + 63) / 64;
  const int aggBlocks = (N + 7) / 8;

  for (int layer = 0; layer < NLAYERS; ++layer) {
    const __hip_bfloat16* w0 =
        (layer == 0) ? w0_l0_bf : w0_rest_bf + (size_t)(layer - 1) * 65536;
    const float* b0 = (layer == 0) ? b0_l0 : b0_rest + (size_t)(layer - 1) * 256;
    const __hip_bfloat16* w1 =
        (layer == 0) ? w1_l0_bf : w1_rest_bf + (size_t)(layer - 1) * 65536;
    const float* b1 = (layer == 0) ? b1_l0 : b1_rest + (size_t)(layer - 1) * 256;

    if (layer == 0) {
      aggregate<D_IN><<<aggBlocks, 256, 0, stream>>>(xb, csr, row_start, deg,
                                                     eps_all, layer, pre, N);
      gin_mlp<D_IN, true><<<gemmBlocks, 256, 0, stream>>>(
          (const __hip_bfloat16*)pre, w0, b0, w1, b1, h, N);
    } else {
      aggregate<D_H><<<aggBlocks, 256, 0, stream>>>(h, csr, row_start, deg,
                                                    eps_all, layer, pre, N);
      if (layer == NLAYERS - 1)
        gin_mlp<D_H, false><<<gemmBlocks, 256, 0, stream>>>(
            (const __hip_bfloat16*)pre, w0, b0, w1, b1, d_out, N);
      else
        gin_mlp<D_H, true><<<gemmBlocks, 256, 0, stream>>>(
            (const __hip_bfloat16*)pre, w0, b0, w1, b1, h, N);
    }
  }
}

// Round 11
// 605.154 us; speedup vs baseline: 1.0976x; 1.0066x over previous
//
#include <hip/hip_runtime.h>
#include <hip/hip_bf16.h>
#include <stdint.h>

#define D_IN 128
#define D_H 256
#define NLAYERS 5

typedef __bf16 bf16x8 __attribute__((ext_vector_type(8)));
typedef float f32x4 __attribute__((ext_vector_type(4)));
typedef unsigned short u16x8 __attribute__((ext_vector_type(8)));

__device__ inline unsigned short bfbits(float f) {
  __hip_bfloat16 h = __float2bfloat16(f);
  unsigned short s;
  __builtin_memcpy(&s, &h, 2);
  return s;
}

__device__ inline unsigned packbf(float lo, float hi) {
  return (unsigned)bfbits(lo) | ((unsigned)bfbits(hi) << 16);
}

// u holds 2 bf16 (lo in bits 0..15). Accumulate both into a,b.
__device__ inline void addbf2(float& a, float& b, unsigned u) {
  a += __uint_as_float(u << 16);
  b += __uint_as_float(u & 0xffff0000u);
}

__device__ inline void addbf2s(float& a, float& b, unsigned u, float s) {
  a += s * __uint_as_float(u << 16);
  b += s * __uint_as_float(u & 0xffff0000u);
}

// cast x (nx floats) and the 4 weight tensors to bf16, one launch
__global__ void conv_inputs(const float* __restrict__ x, const float* __restrict__ a,
                            const float* __restrict__ b, const float* __restrict__ c,
                            const float* __restrict__ d,
                            __hip_bfloat16* __restrict__ xb,
                            __hip_bfloat16* __restrict__ wb, int nx) {
  int gid = blockIdx.x * blockDim.x + threadIdx.x;
  if (gid < nx) {
    xb[gid] = __float2bfloat16(x[gid]);
    return;
  }
  gid -= nx;
  if (gid >= 622592) return;
  float v;
  if (gid < 32768) v = a[gid];
  else if (gid < 98304) v = b[gid - 32768];
  else if (gid < 360448) v = c[gid - 98304];
  else v = d[gid - 360448];
  wb[gid] = __float2bfloat16(v);
}

__global__ void zero_ints(int* __restrict__ p, int n) {
  int i = blockIdx.x * blockDim.x + threadIdx.x;
  if (i < n) p[i] = 0;
}

// ---- CSR build ----
__global__ void hist_kernel(const int* __restrict__ ei, int E, int* __restrict__ deg) {
  int e = blockIdx.x * blockDim.x + threadIdx.x;
  if (e < E) atomicAdd(&deg[ei[E + e]], 1);
}

__global__ __launch_bounds__(256) void block_sums(const int* __restrict__ deg,
                                                  int* __restrict__ bsum, int N) {
  int t = threadIdx.x;
  int idx = blockIdx.x * 1024 + t * 4;
  int4 v = {0, 0, 0, 0};
  if (idx + 3 < N) v = *reinterpret_cast<const int4*>(deg + idx);
  else {
    if (idx + 0 < N) v.x = deg[idx + 0];
    if (idx + 1 < N) v.y = deg[idx + 1];
    if (idx + 2 < N) v.z = deg[idx + 2];
    if (idx + 3 < N) v.w = deg[idx + 3];
  }
  int s = v.x + v.y + v.z + v.w;
#pragma unroll
  for (int off = 32; off > 0; off >>= 1) s += __shfl_down(s, off);
  __shared__ int ws[4];
  int lane = t & 63, w = t >> 6;
  if (lane == 0) ws[w] = s;
  __syncthreads();
  if (t == 0) bsum[blockIdx.x] = ws[0] + ws[1] + ws[2] + ws[3];
}

__global__ void scan_bsums(int* __restrict__ bsum, int nb) {
  int t = threadIdx.x;
  int orig = (t < nb) ? bsum[t] : 0;
  int v = orig;
#pragma unroll
  for (int off = 1; off < 64; off <<= 1) {
    int u = __shfl_up(v, off);
    if (t >= off) v += u;
  }
  if (t < nb) bsum[t] = v - orig;  // exclusive
}

__global__ __launch_bounds__(256) void scan_apply(const int* __restrict__ deg,
                                                  const int* __restrict__ bsum_ex,
                                                  int* __restrict__ row_start, int N) {
  int t = threadIdx.x;
  int idx = blockIdx.x * 1024 + t * 4;
  int4 v = {0, 0, 0, 0};
  if (idx + 3 < N) v = *reinterpret_cast<const int4*>(deg + idx);
  else {
    if (idx + 0 < N) v.x = deg[idx + 0];
    if (idx + 1 < N) v.y = deg[idx + 1];
    if (idx + 2 < N) v.z = deg[idx + 2];
    if (idx + 3 < N) v.w = deg[idx + 3];
  }
  int s = v.x + v.y + v.z + v.w;
  int lane = t & 63, w = t >> 6;
  int sc = s;
#pragma unroll
  for (int off = 1; off < 64; off <<= 1) {
    int u = __shfl_up(sc, off);
    if (lane >= off) sc += u;
  }
  __shared__ int woff[4];
  if (lane == 63) woff[w] = sc;
  __syncthreads();
  int boff = bsum_ex[blockIdx.x];
#pragma unroll
  for (int i = 0; i < 4; ++i)
    if (i < w) boff += woff[i];
  int ex = boff + sc - s;
  if (idx + 3 < N) {
    int4 o;
    o.x = ex;
    o.y = ex + v.x;
    o.z = ex + v.x + v.y;
    o.w = ex + v.x + v.y + v.z;
    *reinterpret_cast<int4*>(row_start + idx) = o;
  } else {
    if (idx + 0 < N) row_start[idx + 0] = ex;
    if (idx + 1 < N) row_start[idx + 1] = ex + v.x;
    if (idx + 2 < N) row_start[idx + 2] = ex + v.x + v.y;
    if (idx + 3 < N) row_start[idx + 3] = ex + v.x + v.y + v.z;
  }
}

__global__ void fill_kernel(const int* __restrict__ ei, int E,
                            const int* __restrict__ row_start,
                            int* __restrict__ cursor, int* __restrict__ csr) {
  int e = blockIdx.x * blockDim.x + threadIdx.x;
  if (e >= E) return;
  int d = ei[E + e];
  int p = atomicAdd(&cursor[d], 1);
  csr[row_start[d] + p] = ei[e];
}

// ---- aggregation: pre[n] = bf16( (1+eps)*h[n] + sum_{s in in(n)} h[s] ) ----
// All-bf16 input. Half-wave (32 lanes) per node; indices broadcast via shfl;
// 8 rows in flight.
template <int D>
__global__ __launch_bounds__(256) void aggregate(const unsigned short* __restrict__ hb,
                                                 const int* __restrict__ csr,
                                                 const int* __restrict__ row_start,
                                                 const int* __restrict__ deg,
                                                 const float* __restrict__ eps_all,
                                                 int layer,
                                                 unsigned short* __restrict__ pre,
                                                 int N) {
  constexpr int PL = D / 32;  // ushorts per lane: 4 or 8
  const int half = threadIdx.x >> 5;
  const int lane = threadIdx.x & 31;
  const int node = blockIdx.x * 8 + half;
  if (node >= N) return;

  const int start = row_start[node];
  const int cnt = deg[node];
  const float epsv = 1.0f + eps_all[layer];

  float acc[PL];
#pragma unroll
  for (int j = 0; j < PL; ++j) acc[j] = 0.0f;

  if (D == 256) {
    uint4 su = *reinterpret_cast<const uint4*>(hb + (size_t)node * D + lane * 8);
    for (int base = 0; base < cnt; base += 32) {
      int m = cnt - base;
      if (m > 32) m = 32;
      int idx = (lane < m) ? csr[start + base + lane] : 0;
      int i = 0;
      for (; i + 8 <= m; i += 8) {
        uint4 q[8];
#pragma unroll
        for (int r = 0; r < 8; ++r) {
          int s = __shfl(idx, i + r, 32);
          q[r] = *reinterpret_cast<const uint4*>(hb + (size_t)s * D + lane * 8);
        }
#pragma unroll
        for (int r = 0; r < 8; ++r) {
          addbf2(acc[0], acc[1], q[r].x);
          addbf2(acc[2], acc[3], q[r].y);
          addbf2(acc[4], acc[5], q[r].z);
          addbf2(acc[6], acc[7], q[r].w);
        }
      }
      for (; i + 4 <= m; i += 4) {
        uint4 q[4];
#pragma unroll
        for (int r = 0; r < 4; ++r) {
          int s = __shfl(idx, i + r, 32);
          q[r] = *reinterpret_cast<const uint4*>(hb + (size_t)s * D + lane * 8);
        }
#pragma unroll
        for (int r = 0; r < 4; ++r) {
          addbf2(acc[0], acc[1], q[r].x);
          addbf2(acc[2], acc[3], q[r].y);
          addbf2(acc[4], acc[5], q[r].z);
          addbf2(acc[6], acc[7], q[r].w);
        }
      }
      for (; i < m; ++i) {
        int s = __shfl(idx, i, 32);
        uint4 q = *reinterpret_cast<const uint4*>(hb + (size_t)s * D + lane * 8);
        addbf2(acc[0], acc[1], q.x);
        addbf2(acc[2], acc[3], q.y);
        addbf2(acc[4], acc[5], q.z);
        addbf2(acc[6], acc[7], q.w);
      }
    }
    addbf2s(acc[0], acc[1], su.x, epsv);
    addbf2s(acc[2], acc[3], su.y, epsv);
    addbf2s(acc[4], acc[5], su.z, epsv);
    addbf2s(acc[6], acc[7], su.w, epsv);
    uint4 o;
    o.x = packbf(acc[0], acc[1]);
    o.y = packbf(acc[2], acc[3]);
    o.z = packbf(acc[4], acc[5]);
    o.w = packbf(acc[6], acc[7]);
    *reinterpret_cast<uint4*>(pre + (size_t)node * D + lane * 8) = o;
  } else {  // D == 128
    uint2 su = *reinterpret_cast<const uint2*>(hb + (size_t)node * D + lane * 4);
    for (int base = 0; base < cnt; base += 32) {
      int m = cnt - base;
      if (m > 32) m = 32;
      int idx = (lane < m) ? csr[start + base + lane] : 0;
      int i = 0;
      for (; i + 8 <= m; i += 8) {
        uint2 q[8];
#pragma unroll
        for (int r = 0; r < 8; ++r) {
          int s = __shfl(idx, i + r, 32);
          q[r] = *reinterpret_cast<const uint2*>(hb + (size_t)s * D + lane * 4);
        }
#pragma unroll
        for (int r = 0; r < 8; ++r) {
          addbf2(acc[0], acc[1], q[r].x);
          addbf2(acc[2], acc[3], q[r].y);
        }
      }
      for (; i + 4 <= m; i += 4) {
        uint2 q[4];
#pragma unroll
        for (int r = 0; r < 4; ++r) {
          int s = __shfl(idx, i + r, 32);
          q[r] = *reinterpret_cast<const uint2*>(hb + (size_t)s * D + lane * 4);
        }
#pragma unroll
        for (int r = 0; r < 4; ++r) {
          addbf2(acc[0], acc[1], q[r].x);
          addbf2(acc[2], acc[3], q[r].y);
        }
      }
      for (; i < m; ++i) {
        int s = __shfl(idx, i, 32);
        uint2 q = *reinterpret_cast<const uint2*>(hb + (size_t)s * D + lane * 4);
        addbf2(acc[0], acc[1], q.x);
        addbf2(acc[2], acc[3], q.y);
      }
    }
    addbf2s(acc[0], acc[1], su.x, epsv);
    addbf2s(acc[2], acc[3], su.y, epsv);
    uint2 o;
    o.x = packbf(acc[0], acc[1]);
    o.y = packbf(acc[2], acc[3]);
    *reinterpret_cast<uint2*>(pre + (size_t)node * D + lane * 4) = o;
  }
}

// ---- W-stationary streaming GEMM: out = relu(A @ W.T + bias) ----
// A: [Nrows x K] bf16; W: [256 x K] bf16; out: [Nrows x 256] bf16 or f32.
// Block = 256 thr = 4 waves; wave w owns col-group w (64 cols) and holds ALL
// its W fragments in registers (K=256: 32 x bf16x8 = 128 VGPR) for the whole
// kernel. Waves grid-stride over 32-row A-chunks (all 4 waves of a block read
// the SAME rows -> L1 reuse). Per chunk: 2*NK A-loads then 8*NK MFMAs; no LDS,
// no barriers. __launch_bounds__(256,2) caps VGPR at 256 (2 waves/SIMD).
// mfma_f32_16x16x32_bf16 frag maps: A/B row/col = lane&15, k = (lane>>4)*8 + j;
// C/D: col = lane&15, row = (lane>>4)*4 + reg.
template <int K, bool OUT_BF16>
__global__ __launch_bounds__(256, 2) void wstat_gemm(
    const unsigned short* __restrict__ Ap, const __hip_bfloat16* __restrict__ Wp,
    const float* __restrict__ bias, void* __restrict__ Outp, int Nrows) {
  constexpr int NK = K / 32;
  const int lane = threadIdx.x & 63;
  const int colgroup = threadIdx.x >> 6;  // 0..3
  const int l15 = lane & 15;
  const int kg = lane >> 4;  // 0..3
  const int col0 = colgroup * 64;

  // load W fragments once (register-resident)
  bf16x8 wfr[NK][4];
  const unsigned short* Ws = (const unsigned short*)Wp;
#pragma unroll
  for (int ct = 0; ct < 4; ++ct) {
    const unsigned short* wrow = Ws + (size_t)(col0 + ct * 16 + l15) * K + kg * 8;
#pragma unroll
    for (int kk = 0; kk < NK; ++kk)
      wfr[kk][ct] = *reinterpret_cast<const bf16x8*>(wrow + kk * 32);
  }
  float bv[4];
#pragma unroll
  for (int ct = 0; ct < 4; ++ct) bv[ct] = bias[col0 + ct * 16 + l15];

  const int nchunks = (Nrows + 31) >> 5;
  for (int c = blockIdx.x; c < nchunks; c += gridDim.x) {
    const int r0 = c << 5;
    // load A fragments for the 32-row chunk (16 b128 loads in flight)
    bf16x8 afr[NK][2];
#pragma unroll
    for (int rt = 0; rt < 2; ++rt) {
      int row = r0 + rt * 16 + l15;
      if (row > Nrows - 1) row = Nrows - 1;  // clamp: dup rows feed masked C
      const unsigned short* ar = Ap + (size_t)row * K + kg * 8;
#pragma unroll
      for (int kk = 0; kk < NK; ++kk)
        afr[kk][rt] = *reinterpret_cast<const bf16x8*>(ar + kk * 32);
    }
    f32x4 acc[2][4];
#pragma unroll
    for (int rt = 0; rt < 2; ++rt)
#pragma unroll
      for (int ct = 0; ct < 4; ++ct) acc[rt][ct] = 0.0f;
#pragma unroll
    for (int kk = 0; kk < NK; ++kk)
#pragma unroll
      for (int rt = 0; rt < 2; ++rt)
#pragma unroll
        for (int ct = 0; ct < 4; ++ct)
          acc[rt][ct] = __builtin_amdgcn_mfma_f32_16x16x32_bf16(
              afr[kk][rt], wfr[kk][ct], acc[rt][ct], 0, 0, 0);
    // epilogue: bias + relu + store
#pragma unroll
    for (int ct = 0; ct < 4; ++ct) {
      int col = col0 + ct * 16 + l15;
#pragma unroll
      for (int rt = 0; rt < 2; ++rt)
#pragma unroll
        for (int i = 0; i < 4; ++i) {
          int row = r0 + rt * 16 + kg * 4 + i;
          if (row < Nrows) {
            float v = fmaxf(acc[rt][ct][i] + bv[ct], 0.0f);
            if (OUT_BF16)
              ((__hip_bfloat16*)Outp)[(size_t)row * D_H + col] = __float2bfloat16(v);
            else
              ((float*)Outp)[(size_t)row * D_H + col] = v;
          }
        }
    }
  }
}

extern "C" void kernel_launch(void* const* d_in, const int* in_sizes, int n_in,
                              void* d_out, int out_size, void* d_ws, size_t ws_size,
                              hipStream_t stream) {
  const float* x = (const float*)d_in[0];
  const int* ei = (const int*)d_in[1];  // [2, E]: row0 = src, row1 = dst
  const float* eps_all = (const float*)d_in[2];
  const float* w0_l0 = (const float*)d_in[3];
  const float* b0_l0 = (const float*)d_in[4];
  const float* w1_l0 = (const float*)d_in[5];
  const float* b1_l0 = (const float*)d_in[6];
  const float* w0_rest = (const float*)d_in[7];
  const float* b0_rest = (const float*)d_in[8];
  const float* w1_rest = (const float*)d_in[9];
  const float* b1_rest = (const float*)d_in[10];

  const int N = in_sizes[0] / D_IN;  // 50000
  const int E = in_sizes[1] / 2;     // 800000
  const int NX = N * D_IN;           // x elements

  char* ws = (char*)d_ws;
  const size_t node_bf = (size_t)N * D_H * sizeof(unsigned short);  // 25.6 MB
  unsigned short* h = (unsigned short*)ws;                 // layer outputs
  unsigned short* pre = (unsigned short*)(ws + node_bf);   // aggregate out
  unsigned short* mid = (unsigned short*)(ws + 2 * node_bf);  // gemm0 out
  unsigned short* xb = (unsigned short*)(ws + 3 * node_bf);   // x cast to bf16
  char* p = ws + 3 * node_bf + (size_t)NX * sizeof(unsigned short);
  __hip_bfloat16* wbf = (__hip_bfloat16*)p;
  p += 622592 * sizeof(__hip_bfloat16);
  int* deg = (int*)p;           // [N]
  int* cursor = deg + N;        // [N]
  int* row_start = cursor + N;  // [N]
  int* bsum = row_start + N;    // [64]
  int* csr = bsum + 64;         // [E]

  __hip_bfloat16* w0_l0_bf = wbf;
  __hip_bfloat16* w1_l0_bf = wbf + 32768;
  __hip_bfloat16* w0_rest_bf = wbf + 98304;
  __hip_bfloat16* w1_rest_bf = w0_rest_bf + 262144;

  conv_inputs<<<(NX + 622592 + 255) / 256, 256, 0, stream>>>(
      x, w0_l0, w1_l0, w0_rest, w1_rest, (__hip_bfloat16*)xb, wbf, NX);

  // CSR build
  const int nb = (N + 1023) / 1024;  // 49
  zero_ints<<<(2 * N + 255) / 256, 256, 0, stream>>>(deg, 2 * N);  // deg + cursor
  hist_kernel<<<(E + 255) / 256, 256, 0, stream>>>(ei, E, deg);
  block_sums<<<nb, 256, 0, stream>>>(deg, bsum, N);
  scan_bsums<<<1, 64, 0, stream>>>(bsum, nb);
  scan_apply<<<nb, 256, 0, stream>>>(deg, bsum, row_start, N);
  fill_kernel<<<(E + 255) / 256, 256, 0, stream>>>(ei, E, row_start, cursor, csr);

  const int gemmGrid = 512;  // 2048 waves = 2/SIMD x 4 SIMD x 256 CU
  const int aggBlocks = (N + 7) / 8;

  for (int layer = 0; layer < NLAYERS; ++layer) {
    const __hip_bfloat16* w0 =
        (layer == 0) ? w0_l0_bf : w0_rest_bf + (size_t)(layer - 1) * 65536;
    const float* b0 = (layer == 0) ? b0_l0 : b0_rest + (size_t)(layer - 1) * 256;
    const __hip_bfloat16* w1 =
        (layer == 0) ? w1_l0_bf : w1_rest_bf + (size_t)(layer - 1) * 65536;
    const float* b1 = (layer == 0) ? b1_l0 : b1_rest + (size_t)(layer - 1) * 256;

    if (layer == 0) {
      aggregate<D_IN><<<aggBlocks, 256, 0, stream>>>(xb, csr, row_start, deg,
                                                     eps_all, layer, pre, N);
      wstat_gemm<D_IN, true><<<gemmGrid, 256, 0, stream>>>(pre, w0, b0, mid, N);
    } else {
      aggregate<D_H><<<aggBlocks, 256, 0, stream>>>(h, csr, row_start, deg,
                                                    eps_all, layer, pre, N);
      wstat_gemm<D_H, true><<<gemmGrid, 256, 0, stream>>>(pre, w0, b0, mid, N);
    }
    if (layer == NLAYERS - 1)
      wstat_gemm<D_H, false><<<gemmGrid, 256, 0, stream>>>(mid, w1, b1, d_out, N);
    else
      wstat_gemm<D_H, true><<<gemmGrid, 256, 0, stream>>>(mid, w1, b1, h, N);
  }
}

// Round 12
// 519.652 us; speedup vs baseline: 1.2781x; 1.1645x over previous
//
#include <hip/hip_runtime.h>
#include <hip/hip_bf16.h>
#include <stdint.h>

#define D_IN 128
#define D_H 256
#define NLAYERS 5

typedef __bf16 bf16x8 __attribute__((ext_vector_type(8)));
typedef float f32x4 __attribute__((ext_vector_type(4)));
typedef unsigned short u16x8 __attribute__((ext_vector_type(8)));

// LDS tile row stride in ushorts: 260 u16 = 520 B; 130 dwords, 130%32==2 ->
// consecutive rows spread across banks (measured ~0 conflicts).
#define MID_STRIDE 260

__device__ inline unsigned short bfbits(float f) {
  __hip_bfloat16 h = __float2bfloat16(f);
  unsigned short s;
  __builtin_memcpy(&s, &h, 2);
  return s;
}

__device__ inline unsigned packbf(float lo, float hi) {
  return (unsigned)bfbits(lo) | ((unsigned)bfbits(hi) << 16);
}

// u holds 2 bf16 (lo in bits 0..15). Accumulate both into a,b.
__device__ inline void addbf2(float& a, float& b, unsigned u) {
  a += __uint_as_float(u << 16);
  b += __uint_as_float(u & 0xffff0000u);
}

__device__ inline void addbf2s(float& a, float& b, unsigned u, float s) {
  a += s * __uint_as_float(u << 16);
  b += s * __uint_as_float(u & 0xffff0000u);
}

// cast x (nx floats) and the 4 weight tensors to bf16, one launch
__global__ void conv_inputs(const float* __restrict__ x, const float* __restrict__ a,
                            const float* __restrict__ b, const float* __restrict__ c,
                            const float* __restrict__ d,
                            __hip_bfloat16* __restrict__ xb,
                            __hip_bfloat16* __restrict__ wb, int nx) {
  int gid = blockIdx.x * blockDim.x + threadIdx.x;
  if (gid < nx) {
    xb[gid] = __float2bfloat16(x[gid]);
    return;
  }
  gid -= nx;
  if (gid >= 622592) return;
  float v;
  if (gid < 32768) v = a[gid];
  else if (gid < 98304) v = b[gid - 32768];
  else if (gid < 360448) v = c[gid - 98304];
  else v = d[gid - 360448];
  wb[gid] = __float2bfloat16(v);
}

__global__ void zero_ints(int* __restrict__ p, int n) {
  int i = blockIdx.x * blockDim.x + threadIdx.x;
  if (i < n) p[i] = 0;
}

// ---- CSR build ----
__global__ void hist_kernel(const int* __restrict__ ei, int E, int* __restrict__ deg) {
  int e = blockIdx.x * blockDim.x + threadIdx.x;
  if (e < E) atomicAdd(&deg[ei[E + e]], 1);
}

__global__ __launch_bounds__(256) void block_sums(const int* __restrict__ deg,
                                                  int* __restrict__ bsum, int N) {
  int t = threadIdx.x;
  int idx = blockIdx.x * 1024 + t * 4;
  int4 v = {0, 0, 0, 0};
  if (idx + 3 < N) v = *reinterpret_cast<const int4*>(deg + idx);
  else {
    if (idx + 0 < N) v.x = deg[idx + 0];
    if (idx + 1 < N) v.y = deg[idx + 1];
    if (idx + 2 < N) v.z = deg[idx + 2];
    if (idx + 3 < N) v.w = deg[idx + 3];
  }
  int s = v.x + v.y + v.z + v.w;
#pragma unroll
  for (int off = 32; off > 0; off >>= 1) s += __shfl_down(s, off);
  __shared__ int ws[4];
  int lane = t & 63, w = t >> 6;
  if (lane == 0) ws[w] = s;
  __syncthreads();
  if (t == 0) bsum[blockIdx.x] = ws[0] + ws[1] + ws[2] + ws[3];
}

__global__ void scan_bsums(int* __restrict__ bsum, int nb) {
  int t = threadIdx.x;
  int orig = (t < nb) ? bsum[t] : 0;
  int v = orig;
#pragma unroll
  for (int off = 1; off < 64; off <<= 1) {
    int u = __shfl_up(v, off);
    if (t >= off) v += u;
  }
  if (t < nb) bsum[t] = v - orig;  // exclusive
}

__global__ __launch_bounds__(256) void scan_apply(const int* __restrict__ deg,
                                                  const int* __restrict__ bsum_ex,
                                                  int* __restrict__ row_start, int N) {
  int t = threadIdx.x;
  int idx = blockIdx.x * 1024 + t * 4;
  int4 v = {0, 0, 0, 0};
  if (idx + 3 < N) v = *reinterpret_cast<const int4*>(deg + idx);
  else {
    if (idx + 0 < N) v.x = deg[idx + 0];
    if (idx + 1 < N) v.y = deg[idx + 1];
    if (idx + 2 < N) v.z = deg[idx + 2];
    if (idx + 3 < N) v.w = deg[idx + 3];
  }
  int s = v.x + v.y + v.z + v.w;
  int lane = t & 63, w = t >> 6;
  int sc = s;
#pragma unroll
  for (int off = 1; off < 64; off <<= 1) {
    int u = __shfl_up(sc, off);
    if (lane >= off) sc += u;
  }
  __shared__ int woff[4];
  if (lane == 63) woff[w] = sc;
  __syncthreads();
  int boff = bsum_ex[blockIdx.x];
#pragma unroll
  for (int i = 0; i < 4; ++i)
    if (i < w) boff += woff[i];
  int ex = boff + sc - s;
  if (idx + 3 < N) {
    int4 o;
    o.x = ex;
    o.y = ex + v.x;
    o.z = ex + v.x + v.y;
    o.w = ex + v.x + v.y + v.z;
    *reinterpret_cast<int4*>(row_start + idx) = o;
  } else {
    if (idx + 0 < N) row_start[idx + 0] = ex;
    if (idx + 1 < N) row_start[idx + 1] = ex + v.x;
    if (idx + 2 < N) row_start[idx + 2] = ex + v.x + v.y;
    if (idx + 3 < N) row_start[idx + 3] = ex + v.x + v.y + v.z;
  }
}

__global__ void fill_kernel(const int* __restrict__ ei, int E,
                            const int* __restrict__ row_start,
                            int* __restrict__ cursor, int* __restrict__ csr) {
  int e = blockIdx.x * blockDim.x + threadIdx.x;
  if (e >= E) return;
  int d = ei[E + e];
  int p = atomicAdd(&cursor[d], 1);
  csr[row_start[d] + p] = ei[e];
}

// ---- aggregation: pre[n] = bf16( (1+eps)*h[n] + sum_{s in in(n)} h[s] ) ----
// All-bf16 input. Half-wave (32 lanes) per node; indices broadcast via shfl;
// 8 rows in flight.
template <int D>
__global__ __launch_bounds__(256) void aggregate(const unsigned short* __restrict__ hb,
                                                 const int* __restrict__ csr,
                                                 const int* __restrict__ row_start,
                                                 const int* __restrict__ deg,
                                                 const float* __restrict__ eps_all,
                                                 int layer,
                                                 unsigned short* __restrict__ pre,
                                                 int N) {
  constexpr int PL = D / 32;  // ushorts per lane: 4 or 8
  const int half = threadIdx.x >> 5;
  const int lane = threadIdx.x & 31;
  const int node = blockIdx.x * 8 + half;
  if (node >= N) return;

  const int start = row_start[node];
  const int cnt = deg[node];
  const float epsv = 1.0f + eps_all[layer];

  float acc[PL];
#pragma unroll
  for (int j = 0; j < PL; ++j) acc[j] = 0.0f;

  if (D == 256) {
    uint4 su = *reinterpret_cast<const uint4*>(hb + (size_t)node * D + lane * 8);
    for (int base = 0; base < cnt; base += 32) {
      int m = cnt - base;
      if (m > 32) m = 32;
      int idx = (lane < m) ? csr[start + base + lane] : 0;
      int i = 0;
      for (; i + 8 <= m; i += 8) {
        uint4 q[8];
#pragma unroll
        for (int r = 0; r < 8; ++r) {
          int s = __shfl(idx, i + r, 32);
          q[r] = *reinterpret_cast<const uint4*>(hb + (size_t)s * D + lane * 8);
        }
#pragma unroll
        for (int r = 0; r < 8; ++r) {
          addbf2(acc[0], acc[1], q[r].x);
          addbf2(acc[2], acc[3], q[r].y);
          addbf2(acc[4], acc[5], q[r].z);
          addbf2(acc[6], acc[7], q[r].w);
        }
      }
      for (; i + 4 <= m; i += 4) {
        uint4 q[4];
#pragma unroll
        for (int r = 0; r < 4; ++r) {
          int s = __shfl(idx, i + r, 32);
          q[r] = *reinterpret_cast<const uint4*>(hb + (size_t)s * D + lane * 8);
        }
#pragma unroll
        for (int r = 0; r < 4; ++r) {
          addbf2(acc[0], acc[1], q[r].x);
          addbf2(acc[2], acc[3], q[r].y);
          addbf2(acc[4], acc[5], q[r].z);
          addbf2(acc[6], acc[7], q[r].w);
        }
      }
      for (; i < m; ++i) {
        int s = __shfl(idx, i, 32);
        uint4 q = *reinterpret_cast<const uint4*>(hb + (size_t)s * D + lane * 8);
        addbf2(acc[0], acc[1], q.x);
        addbf2(acc[2], acc[3], q.y);
        addbf2(acc[4], acc[5], q.z);
        addbf2(acc[6], acc[7], q.w);
      }
    }
    addbf2s(acc[0], acc[1], su.x, epsv);
    addbf2s(acc[2], acc[3], su.y, epsv);
    addbf2s(acc[4], acc[5], su.z, epsv);
    addbf2s(acc[6], acc[7], su.w, epsv);
    uint4 o;
    o.x = packbf(acc[0], acc[1]);
    o.y = packbf(acc[2], acc[3]);
    o.z = packbf(acc[4], acc[5]);
    o.w = packbf(acc[6], acc[7]);
    *reinterpret_cast<uint4*>(pre + (size_t)node * D + lane * 8) = o;
  } else {  // D == 128
    uint2 su = *reinterpret_cast<const uint2*>(hb + (size_t)node * D + lane * 4);
    for (int base = 0; base < cnt; base += 32) {
      int m = cnt - base;
      if (m > 32) m = 32;
      int idx = (lane < m) ? csr[start + base + lane] : 0;
      int i = 0;
      for (; i + 8 <= m; i += 8) {
        uint2 q[8];
#pragma unroll
        for (int r = 0; r < 8; ++r) {
          int s = __shfl(idx, i + r, 32);
          q[r] = *reinterpret_cast<const uint2*>(hb + (size_t)s * D + lane * 4);
        }
#pragma unroll
        for (int r = 0; r < 8; ++r) {
          addbf2(acc[0], acc[1], q[r].x);
          addbf2(acc[2], acc[3], q[r].y);
        }
      }
      for (; i + 4 <= m; i += 4) {
        uint2 q[4];
#pragma unroll
        for (int r = 0; r < 4; ++r) {
          int s = __shfl(idx, i + r, 32);
          q[r] = *reinterpret_cast<const uint2*>(hb + (size_t)s * D + lane * 4);
        }
#pragma unroll
        for (int r = 0; r < 4; ++r) {
          addbf2(acc[0], acc[1], q[r].x);
          addbf2(acc[2], acc[3], q[r].y);
        }
      }
      for (; i < m; ++i) {
        int s = __shfl(idx, i, 32);
        uint2 q = *reinterpret_cast<const uint2*>(hb + (size_t)s * D + lane * 4);
        addbf2(acc[0], acc[1], q.x);
        addbf2(acc[2], acc[3], q.y);
      }
    }
    addbf2s(acc[0], acc[1], su.x, epsv);
    addbf2s(acc[2], acc[3], su.y, epsv);
    uint2 o;
    o.x = packbf(acc[0], acc[1]);
    o.y = packbf(acc[2], acc[3]);
    *reinterpret_cast<uint2*>(pre + (size_t)node * D + lane * 4) = o;
  }
}

// ---- producer-consumer fused MLP: out = relu( relu(A@W0.T+b0) @ W1.T + b1 ) ----
// Block = 512 thr = 8 waves, one block per CU (grid 256).
// Waves 0-3 (producers): hold their 64-col quarter of W0 in registers; per
//   32-row chunk: load A frags from global, 64 MFMAs, write mid=relu(.+b0)
//   as bf16 into a double-buffered LDS tile.
// Waves 4-7 (consumers): hold their 64-col quarter of W1 in registers; MFMA
//   the LDS mid tile, store out. One __syncthreads per chunk, alternating
//   buffers -> produce(c+1) overlaps consume(c); each SIMD runs 1 producer +
//   1 consumer wave (MFMA/VMEM overlap).
// mfma_f32_16x16x32_bf16 frag maps: A/B row/col = lane&15, k = (lane>>4)*8+j;
// C/D: col = lane&15, row = (lane>>4)*4 + reg.
template <int K0, bool OUT_BF16>
__global__ __launch_bounds__(512, 2) void mlp_fused(
    const unsigned short* __restrict__ Ap, const __hip_bfloat16* __restrict__ W0p,
    const float* __restrict__ b0, const __hip_bfloat16* __restrict__ W1p,
    const float* __restrict__ b1, void* __restrict__ Outp, int Nrows) {
  __shared__ unsigned short midb[2][32 * MID_STRIDE];  // 33.3 KB

  constexpr int NK0 = K0 / 32;
  constexpr int NK1 = D_H / 32;
  const int tid = threadIdx.x;
  const int wid = tid >> 6;        // 0..7
  const bool prod = (wid < 4);
  const int cg = wid & 3;          // col-group
  const int lane = tid & 63;
  const int l15 = lane & 15;
  const int kg = lane >> 4;
  const int col0 = cg * 64;
  const int nch = (Nrows + 31) >> 5;

  // register-resident W quarter + bias
  bf16x8 wfr[NK1][4];
  float bv[4];
  if (prod) {
    const unsigned short* Ws = (const unsigned short*)W0p;
#pragma unroll
    for (int ct = 0; ct < 4; ++ct) {
      const unsigned short* wrow = Ws + (size_t)(col0 + ct * 16 + l15) * K0 + kg * 8;
#pragma unroll
      for (int kk = 0; kk < NK0; ++kk)
        wfr[kk][ct] = *reinterpret_cast<const bf16x8*>(wrow + kk * 32);
      bv[ct] = b0[col0 + ct * 16 + l15];
    }
  } else {
    const unsigned short* Ws = (const unsigned short*)W1p;
#pragma unroll
    for (int ct = 0; ct < 4; ++ct) {
      const unsigned short* wrow = Ws + (size_t)(col0 + ct * 16 + l15) * D_H + kg * 8;
#pragma unroll
      for (int kk = 0; kk < NK1; ++kk)
        wfr[kk][ct] = *reinterpret_cast<const bf16x8*>(wrow + kk * 32);
      bv[ct] = b1[col0 + ct * 16 + l15];
    }
  }

  auto produce = [&](int c, unsigned short* buf) {
    const int r0 = c << 5;
    bf16x8 afr[NK0][2];
#pragma unroll
    for (int rt = 0; rt < 2; ++rt) {
      int row = r0 + rt * 16 + l15;
      if (row > Nrows - 1) row = Nrows - 1;  // clamp: dup rows feed masked C
      const unsigned short* ar = Ap + (size_t)row * K0 + kg * 8;
#pragma unroll
      for (int kk = 0; kk < NK0; ++kk)
        afr[kk][rt] = *reinterpret_cast<const bf16x8*>(ar + kk * 32);
    }
    f32x4 acc[2][4];
#pragma unroll
    for (int rt = 0; rt < 2; ++rt)
#pragma unroll
      for (int ct = 0; ct < 4; ++ct) acc[rt][ct] = 0.0f;
#pragma unroll
    for (int kk = 0; kk < NK0; ++kk)
#pragma unroll
      for (int rt = 0; rt < 2; ++rt)
#pragma unroll
        for (int ct = 0; ct < 4; ++ct)
          acc[rt][ct] = __builtin_amdgcn_mfma_f32_16x16x32_bf16(
              afr[kk][rt], wfr[kk][ct], acc[rt][ct], 0, 0, 0);
#pragma unroll
    for (int ct = 0; ct < 4; ++ct) {
      int col = col0 + ct * 16 + l15;
#pragma unroll
      for (int rt = 0; rt < 2; ++rt)
#pragma unroll
        for (int i = 0; i < 4; ++i) {
          int row_l = rt * 16 + kg * 4 + i;
          buf[row_l * MID_STRIDE + col] = bfbits(fmaxf(acc[rt][ct][i] + bv[ct], 0.0f));
        }
    }
  };

  auto consume = [&](int c, const unsigned short* buf) {
    const int r0 = c << 5;
    f32x4 acc[2][4];
#pragma unroll
    for (int rt = 0; rt < 2; ++rt)
#pragma unroll
      for (int ct = 0; ct < 4; ++ct) acc[rt][ct] = 0.0f;
#pragma unroll
    for (int kk = 0; kk < NK1; ++kk) {
      bf16x8 mfr[2];
#pragma unroll
      for (int rt = 0; rt < 2; ++rt)
        mfr[rt] = *reinterpret_cast<const bf16x8*>(
            buf + (rt * 16 + l15) * MID_STRIDE + kk * 32 + kg * 8);
#pragma unroll
      for (int rt = 0; rt < 2; ++rt)
#pragma unroll
        for (int ct = 0; ct < 4; ++ct)
          acc[rt][ct] = __builtin_amdgcn_mfma_f32_16x16x32_bf16(
              mfr[rt], wfr[kk][ct], acc[rt][ct], 0, 0, 0);
    }
#pragma unroll
    for (int ct = 0; ct < 4; ++ct) {
      int col = col0 + ct * 16 + l15;
#pragma unroll
      for (int rt = 0; rt < 2; ++rt)
#pragma unroll
        for (int i = 0; i < 4; ++i) {
          int row = r0 + rt * 16 + kg * 4 + i;
          if (row < Nrows) {
            float v = fmaxf(acc[rt][ct][i] + bv[ct], 0.0f);
            if (OUT_BF16)
              ((__hip_bfloat16*)Outp)[(size_t)row * D_H + col] = __float2bfloat16(v);
            else
              ((float*)Outp)[(size_t)row * D_H + col] = v;
          }
        }
    }
  };

  int c_pr = blockIdx.x;
  int c_co = blockIdx.x;
  int pb = 0;
  if (prod && c_pr < nch) produce(c_pr, midb[0]);
  __syncthreads();
  c_pr += gridDim.x;
  while (c_co < nch) {
    if (prod) {
      if (c_pr < nch) produce(c_pr, midb[pb ^ 1]);
    } else {
      consume(c_co, midb[pb]);
    }
    __syncthreads();
    pb ^= 1;
    c_pr += gridDim.x;
    c_co += gridDim.x;
  }
}

extern "C" void kernel_launch(void* const* d_in, const int* in_sizes, int n_in,
                              void* d_out, int out_size, void* d_ws, size_t ws_size,
                              hipStream_t stream) {
  const float* x = (const float*)d_in[0];
  const int* ei = (const int*)d_in[1];  // [2, E]: row0 = src, row1 = dst
  const float* eps_all = (const float*)d_in[2];
  const float* w0_l0 = (const float*)d_in[3];
  const float* b0_l0 = (const float*)d_in[4];
  const float* w1_l0 = (const float*)d_in[5];
  const float* b1_l0 = (const float*)d_in[6];
  const float* w0_rest = (const float*)d_in[7];
  const float* b0_rest = (const float*)d_in[8];
  const float* w1_rest = (const float*)d_in[9];
  const float* b1_rest = (const float*)d_in[10];

  const int N = in_sizes[0] / D_IN;  // 50000
  const int E = in_sizes[1] / 2;     // 800000
  const int NX = N * D_IN;           // x elements

  char* ws = (char*)d_ws;
  const size_t node_bf = (size_t)N * D_H * sizeof(unsigned short);  // 25.6 MB
  unsigned short* h = (unsigned short*)ws;                // layer outputs
  unsigned short* pre = (unsigned short*)(ws + node_bf);  // aggregate out
  unsigned short* xb = (unsigned short*)(ws + 2 * node_bf);  // x cast to bf16
  char* p = ws + 2 * node_bf + (size_t)NX * sizeof(unsigned short);
  __hip_bfloat16* wbf = (__hip_bfloat16*)p;
  p += 622592 * sizeof(__hip_bfloat16);
  int* deg = (int*)p;           // [N]
  int* cursor = deg + N;        // [N]
  int* row_start = cursor + N;  // [N]
  int* bsum = row_start + N;    // [64]
  int* csr = bsum + 64;         // [E]

  __hip_bfloat16* w0_l0_bf = wbf;
  __hip_bfloat16* w1_l0_bf = wbf + 32768;
  __hip_bfloat16* w0_rest_bf = wbf + 98304;
  __hip_bfloat16* w1_rest_bf = w0_rest_bf + 262144;

  conv_inputs<<<(NX + 622592 + 255) / 256, 256, 0, stream>>>(
      x, w0_l0, w1_l0, w0_rest, w1_rest, (__hip_bfloat16*)xb, wbf, NX);

  // CSR build
  const int nb = (N + 1023) / 1024;  // 49
  zero_ints<<<(2 * N + 255) / 256, 256, 0, stream>>>(deg, 2 * N);  // deg + cursor
  hist_kernel<<<(E + 255) / 256, 256, 0, stream>>>(ei, E, deg);
  block_sums<<<nb, 256, 0, stream>>>(deg, bsum, N);
  scan_bsums<<<1, 64, 0, stream>>>(bsum, nb);
  scan_apply<<<nb, 256, 0, stream>>>(deg, bsum, row_start, N);
  fill_kernel<<<(E + 255) / 256, 256, 0, stream>>>(ei, E, row_start, cursor, csr);

  const int mlpGrid = 256;  // one 8-wave block per CU
  const int aggBlocks = (N + 7) / 8;

  for (int layer = 0; layer < NLAYERS; ++layer) {
    const __hip_bfloat16* w0 =
        (layer == 0) ? w0_l0_bf : w0_rest_bf + (size_t)(layer - 1) * 65536;
    const float* b0 = (layer == 0) ? b0_l0 : b0_rest + (size_t)(layer - 1) * 256;
    const __hip_bfloat16* w1 =
        (layer == 0) ? w1_l0_bf : w1_rest_bf + (size_t)(layer - 1) * 65536;
    const float* b1 = (layer == 0) ? b1_l0 : b1_rest + (size_t)(layer - 1) * 256;

    if (layer == 0) {
      aggregate<D_IN><<<aggBlocks, 256, 0, stream>>>(xb, csr, row_start, deg,
                                                     eps_all, layer, pre, N);
      mlp_fused<D_IN, true><<<mlpGrid, 512, 0, stream>>>(pre, w0, b0, w1, b1, h, N);
    } else {
      aggregate<D_H><<<aggBlocks, 256, 0, stream>>>(h, csr, row_start, deg,
                                                    eps_all, layer, pre, N);
      if (layer == NLAYERS - 1)
        mlp_fused<D_H, false><<<mlpGrid, 512, 0, stream>>>(pre, w0, b0, w1, b1,
                                                           d_out, N);
      else
        mlp_fused<D_H, true><<<mlpGrid, 512, 0, stream>>>(pre, w0, b0, w1, b1, h, N);
    }
  }
}

// Round 13
// 509.081 us; speedup vs baseline: 1.3047x; 1.0208x over previous
//
#include <hip/hip_runtime.h>
#include <hip/hip_bf16.h>
#include <stdint.h>

#define D_IN 128
#define D_H 256
#define NLAYERS 5

typedef __bf16 bf16x8 __attribute__((ext_vector_type(8)));
typedef float f32x4 __attribute__((ext_vector_type(4)));
typedef unsigned short u16x8 __attribute__((ext_vector_type(8)));

// LDS tile row stride in ushorts: 260 u16 = 520 B; 130 dwords, 130%32==2 ->
// consecutive rows spread across banks (measured ~0 conflicts).
#define MID_STRIDE 260

__device__ inline unsigned short bfbits(float f) {
  __hip_bfloat16 h = __float2bfloat16(f);
  unsigned short s;
  __builtin_memcpy(&s, &h, 2);
  return s;
}

__device__ inline unsigned packbf(float lo, float hi) {
  return (unsigned)bfbits(lo) | ((unsigned)bfbits(hi) << 16);
}

// u holds 2 bf16 (lo in bits 0..15). Accumulate both into a,b.
__device__ inline void addbf2(float& a, float& b, unsigned u) {
  a += __uint_as_float(u << 16);
  b += __uint_as_float(u & 0xffff0000u);
}

__device__ inline void addbf2s(float& a, float& b, unsigned u, float s) {
  a += s * __uint_as_float(u << 16);
  b += s * __uint_as_float(u & 0xffff0000u);
}

// cast x (nx floats) and the 4 weight tensors to bf16, one launch
__global__ void conv_inputs(const float* __restrict__ x, const float* __restrict__ a,
                            const float* __restrict__ b, const float* __restrict__ c,
                            const float* __restrict__ d,
                            __hip_bfloat16* __restrict__ xb,
                            __hip_bfloat16* __restrict__ wb, int nx) {
  int gid = blockIdx.x * blockDim.x + threadIdx.x;
  if (gid < nx) {
    xb[gid] = __float2bfloat16(x[gid]);
    return;
  }
  gid -= nx;
  if (gid >= 622592) return;
  float v;
  if (gid < 32768) v = a[gid];
  else if (gid < 98304) v = b[gid - 32768];
  else if (gid < 360448) v = c[gid - 98304];
  else v = d[gid - 360448];
  wb[gid] = __float2bfloat16(v);
}

__global__ void zero_ints(int* __restrict__ p, int n) {
  int i = blockIdx.x * blockDim.x + threadIdx.x;
  if (i < n) p[i] = 0;
}

// ---- CSR build (XCD-affine dst-partitioned to kill line ping-pong) ----
// grid = 8 ranges x CHUNKS blocks; block (r=bid&7, chunk=bid>>3) reads its
// ei chunk and only touches deg/csr entries with dst in range r. With the
// round-robin bid->XCD mapping, atomics/writes stay in one XCD's L2.
#define CSR_CHUNKS 128

__global__ __launch_bounds__(256) void hist_kernel(const int* __restrict__ ei, int E,
                                                   int* __restrict__ deg, int N) {
  const int r = blockIdx.x & 7;
  const int chunk = blockIdx.x >> 3;
  const int rsize = (N + 7) >> 3;
  const int lo = r * rsize;
  const int hi = (lo + rsize < N) ? lo + rsize : N;
  const int stride = CSR_CHUNKS * 256;
  for (int e = chunk * 256 + threadIdx.x; e < E; e += stride) {
    int d = ei[E + e];
    if (d >= lo && d < hi) atomicAdd(&deg[d], 1);
  }
}

__global__ __launch_bounds__(256) void fill_kernel(const int* __restrict__ ei, int E,
                                                   const int* __restrict__ row_start,
                                                   int* __restrict__ cursor,
                                                   int* __restrict__ csr, int N) {
  const int r = blockIdx.x & 7;
  const int chunk = blockIdx.x >> 3;
  const int rsize = (N + 7) >> 3;
  const int lo = r * rsize;
  const int hi = (lo + rsize < N) ? lo + rsize : N;
  const int stride = CSR_CHUNKS * 256;
  for (int e = chunk * 256 + threadIdx.x; e < E; e += stride) {
    int d = ei[E + e];
    if (d >= lo && d < hi) {
      int p = atomicAdd(&cursor[d], 1);
      csr[row_start[d] + p] = ei[e];
    }
  }
}

__global__ __launch_bounds__(256) void block_sums(const int* __restrict__ deg,
                                                  int* __restrict__ bsum, int N) {
  int t = threadIdx.x;
  int idx = blockIdx.x * 1024 + t * 4;
  int4 v = {0, 0, 0, 0};
  if (idx + 3 < N) v = *reinterpret_cast<const int4*>(deg + idx);
  else {
    if (idx + 0 < N) v.x = deg[idx + 0];
    if (idx + 1 < N) v.y = deg[idx + 1];
    if (idx + 2 < N) v.z = deg[idx + 2];
    if (idx + 3 < N) v.w = deg[idx + 3];
  }
  int s = v.x + v.y + v.z + v.w;
#pragma unroll
  for (int off = 32; off > 0; off >>= 1) s += __shfl_down(s, off);
  __shared__ int ws[4];
  int lane = t & 63, w = t >> 6;
  if (lane == 0) ws[w] = s;
  __syncthreads();
  if (t == 0) bsum[blockIdx.x] = ws[0] + ws[1] + ws[2] + ws[3];
}

__global__ void scan_bsums(int* __restrict__ bsum, int nb) {
  int t = threadIdx.x;
  int orig = (t < nb) ? bsum[t] : 0;
  int v = orig;
#pragma unroll
  for (int off = 1; off < 64; off <<= 1) {
    int u = __shfl_up(v, off);
    if (t >= off) v += u;
  }
  if (t < nb) bsum[t] = v - orig;  // exclusive
}

__global__ __launch_bounds__(256) void scan_apply(const int* __restrict__ deg,
                                                  const int* __restrict__ bsum_ex,
                                                  int* __restrict__ row_start, int N) {
  int t = threadIdx.x;
  int idx = blockIdx.x * 1024 + t * 4;
  int4 v = {0, 0, 0, 0};
  if (idx + 3 < N) v = *reinterpret_cast<const int4*>(deg + idx);
  else {
    if (idx + 0 < N) v.x = deg[idx + 0];
    if (idx + 1 < N) v.y = deg[idx + 1];
    if (idx + 2 < N) v.z = deg[idx + 2];
    if (idx + 3 < N) v.w = deg[idx + 3];
  }
  int s = v.x + v.y + v.z + v.w;
  int lane = t & 63, w = t >> 6;
  int sc = s;
#pragma unroll
  for (int off = 1; off < 64; off <<= 1) {
    int u = __shfl_up(sc, off);
    if (lane >= off) sc += u;
  }
  __shared__ int woff[4];
  if (lane == 63) woff[w] = sc;
  __syncthreads();
  int boff = bsum_ex[blockIdx.x];
#pragma unroll
  for (int i = 0; i < 4; ++i)
    if (i < w) boff += woff[i];
  int ex = boff + sc - s;
  if (idx + 3 < N) {
    int4 o;
    o.x = ex;
    o.y = ex + v.x;
    o.z = ex + v.x + v.y;
    o.w = ex + v.x + v.y + v.z;
    *reinterpret_cast<int4*>(row_start + idx) = o;
  } else {
    if (idx + 0 < N) row_start[idx + 0] = ex;
    if (idx + 1 < N) row_start[idx + 1] = ex + v.x;
    if (idx + 2 < N) row_start[idx + 2] = ex + v.x + v.y;
    if (idx + 3 < N) row_start[idx + 3] = ex + v.x + v.y + v.z;
  }
}

// ---- aggregation: pre[n] = bf16( (1+eps)*h[n] + sum_{s in in(n)} h[s] ) ----
// All-bf16 input. Half-wave (32 lanes) per node; indices broadcast via shfl;
// 8 rows in flight.
template <int D>
__global__ __launch_bounds__(256) void aggregate(const unsigned short* __restrict__ hb,
                                                 const int* __restrict__ csr,
                                                 const int* __restrict__ row_start,
                                                 const int* __restrict__ deg,
                                                 const float* __restrict__ eps_all,
                                                 int layer,
                                                 unsigned short* __restrict__ pre,
                                                 int N) {
  constexpr int PL = D / 32;  // ushorts per lane: 4 or 8
  const int half = threadIdx.x >> 5;
  const int lane = threadIdx.x & 31;
  const int node = blockIdx.x * 8 + half;
  if (node >= N) return;

  const int start = row_start[node];
  const int cnt = deg[node];
  const float epsv = 1.0f + eps_all[layer];

  float acc[PL];
#pragma unroll
  for (int j = 0; j < PL; ++j) acc[j] = 0.0f;

  if (D == 256) {
    uint4 su = *reinterpret_cast<const uint4*>(hb + (size_t)node * D + lane * 8);
    for (int base = 0; base < cnt; base += 32) {
      int m = cnt - base;
      if (m > 32) m = 32;
      int idx = (lane < m) ? csr[start + base + lane] : 0;
      int i = 0;
      for (; i + 8 <= m; i += 8) {
        uint4 q[8];
#pragma unroll
        for (int r = 0; r < 8; ++r) {
          int s = __shfl(idx, i + r, 32);
          q[r] = *reinterpret_cast<const uint4*>(hb + (size_t)s * D + lane * 8);
        }
#pragma unroll
        for (int r = 0; r < 8; ++r) {
          addbf2(acc[0], acc[1], q[r].x);
          addbf2(acc[2], acc[3], q[r].y);
          addbf2(acc[4], acc[5], q[r].z);
          addbf2(acc[6], acc[7], q[r].w);
        }
      }
      for (; i + 4 <= m; i += 4) {
        uint4 q[4];
#pragma unroll
        for (int r = 0; r < 4; ++r) {
          int s = __shfl(idx, i + r, 32);
          q[r] = *reinterpret_cast<const uint4*>(hb + (size_t)s * D + lane * 8);
        }
#pragma unroll
        for (int r = 0; r < 4; ++r) {
          addbf2(acc[0], acc[1], q[r].x);
          addbf2(acc[2], acc[3], q[r].y);
          addbf2(acc[4], acc[5], q[r].z);
          addbf2(acc[6], acc[7], q[r].w);
        }
      }
      for (; i < m; ++i) {
        int s = __shfl(idx, i, 32);
        uint4 q = *reinterpret_cast<const uint4*>(hb + (size_t)s * D + lane * 8);
        addbf2(acc[0], acc[1], q.x);
        addbf2(acc[2], acc[3], q.y);
        addbf2(acc[4], acc[5], q.z);
        addbf2(acc[6], acc[7], q.w);
      }
    }
    addbf2s(acc[0], acc[1], su.x, epsv);
    addbf2s(acc[2], acc[3], su.y, epsv);
    addbf2s(acc[4], acc[5], su.z, epsv);
    addbf2s(acc[6], acc[7], su.w, epsv);
    uint4 o;
    o.x = packbf(acc[0], acc[1]);
    o.y = packbf(acc[2], acc[3]);
    o.z = packbf(acc[4], acc[5]);
    o.w = packbf(acc[6], acc[7]);
    *reinterpret_cast<uint4*>(pre + (size_t)node * D + lane * 8) = o;
  } else {  // D == 128
    uint2 su = *reinterpret_cast<const uint2*>(hb + (size_t)node * D + lane * 4);
    for (int base = 0; base < cnt; base += 32) {
      int m = cnt - base;
      if (m > 32) m = 32;
      int idx = (lane < m) ? csr[start + base + lane] : 0;
      int i = 0;
      for (; i + 8 <= m; i += 8) {
        uint2 q[8];
#pragma unroll
        for (int r = 0; r < 8; ++r) {
          int s = __shfl(idx, i + r, 32);
          q[r] = *reinterpret_cast<const uint2*>(hb + (size_t)s * D + lane * 4);
        }
#pragma unroll
        for (int r = 0; r < 8; ++r) {
          addbf2(acc[0], acc[1], q[r].x);
          addbf2(acc[2], acc[3], q[r].y);
        }
      }
      for (; i + 4 <= m; i += 4) {
        uint2 q[4];
#pragma unroll
        for (int r = 0; r < 4; ++r) {
          int s = __shfl(idx, i + r, 32);
          q[r] = *reinterpret_cast<const uint2*>(hb + (size_t)s * D + lane * 4);
        }
#pragma unroll
        for (int r = 0; r < 4; ++r) {
          addbf2(acc[0], acc[1], q[r].x);
          addbf2(acc[2], acc[3], q[r].y);
        }
      }
      for (; i < m; ++i) {
        int s = __shfl(idx, i, 32);
        uint2 q = *reinterpret_cast<const uint2*>(hb + (size_t)s * D + lane * 4);
        addbf2(acc[0], acc[1], q.x);
        addbf2(acc[2], acc[3], q.y);
      }
    }
    addbf2s(acc[0], acc[1], su.x, epsv);
    addbf2s(acc[2], acc[3], su.y, epsv);
    uint2 o;
    o.x = packbf(acc[0], acc[1]);
    o.y = packbf(acc[2], acc[3]);
    *reinterpret_cast<uint2*>(pre + (size_t)node * D + lane * 4) = o;
  }
}

// ---- producer-consumer fused MLP: out = relu( relu(A@W0.T+b0) @ W1.T + b1 ) ----
// Block = 512 thr = 8 waves, one block per CU (grid 256).
// Waves 0-3 (producers): hold their 64-col quarter of W0 in registers; per
//   32-row chunk: load A frags from global, 64 MFMAs, write mid=relu(.+b0)
//   as bf16 into a double-buffered LDS tile.
// Waves 4-7 (consumers): hold their 64-col quarter of W1 in registers; MFMA
//   the LDS mid tile, store out. One __syncthreads per chunk, alternating
//   buffers -> produce(c+1) overlaps consume(c); each SIMD runs 1 producer +
//   1 consumer wave (MFMA/VMEM overlap).
// mfma_f32_16x16x32_bf16 frag maps: A/B row/col = lane&15, k = (lane>>4)*8+j;
// C/D: col = lane&15, row = (lane>>4)*4 + reg.
template <int K0, bool OUT_BF16>
__global__ __launch_bounds__(512, 2) void mlp_fused(
    const unsigned short* __restrict__ Ap, const __hip_bfloat16* __restrict__ W0p,
    const float* __restrict__ b0, const __hip_bfloat16* __restrict__ W1p,
    const float* __restrict__ b1, void* __restrict__ Outp, int Nrows) {
  __shared__ unsigned short midb[2][32 * MID_STRIDE];  // 33.3 KB

  constexpr int NK0 = K0 / 32;
  constexpr int NK1 = D_H / 32;
  const int tid = threadIdx.x;
  const int wid = tid >> 6;        // 0..7
  const bool prod = (wid < 4);
  const int cg = wid & 3;          // col-group
  const int lane = tid & 63;
  const int l15 = lane & 15;
  const int kg = lane >> 4;
  const int col0 = cg * 64;
  const int nch = (Nrows + 31) >> 5;

  // register-resident W quarter + bias
  bf16x8 wfr[NK1][4];
  float bv[4];
  if (prod) {
    const unsigned short* Ws = (const unsigned short*)W0p;
#pragma unroll
    for (int ct = 0; ct < 4; ++ct) {
      const unsigned short* wrow = Ws + (size_t)(col0 + ct * 16 + l15) * K0 + kg * 8;
#pragma unroll
      for (int kk = 0; kk < NK0; ++kk)
        wfr[kk][ct] = *reinterpret_cast<const bf16x8*>(wrow + kk * 32);
      bv[ct] = b0[col0 + ct * 16 + l15];
    }
  } else {
    const unsigned short* Ws = (const unsigned short*)W1p;
#pragma unroll
    for (int ct = 0; ct < 4; ++ct) {
      const unsigned short* wrow = Ws + (size_t)(col0 + ct * 16 + l15) * D_H + kg * 8;
#pragma unroll
      for (int kk = 0; kk < NK1; ++kk)
        wfr[kk][ct] = *reinterpret_cast<const bf16x8*>(wrow + kk * 32);
      bv[ct] = b1[col0 + ct * 16 + l15];
    }
  }

  auto produce = [&](int c, unsigned short* buf) {
    const int r0 = c << 5;
    bf16x8 afr[NK0][2];
#pragma unroll
    for (int rt = 0; rt < 2; ++rt) {
      int row = r0 + rt * 16 + l15;
      if (row > Nrows - 1) row = Nrows - 1;  // clamp: dup rows feed masked C
      const unsigned short* ar = Ap + (size_t)row * K0 + kg * 8;
#pragma unroll
      for (int kk = 0; kk < NK0; ++kk)
        afr[kk][rt] = *reinterpret_cast<const bf16x8*>(ar + kk * 32);
    }
    f32x4 acc[2][4];
#pragma unroll
    for (int rt = 0; rt < 2; ++rt)
#pragma unroll
      for (int ct = 0; ct < 4; ++ct) acc[rt][ct] = 0.0f;
#pragma unroll
    for (int kk = 0; kk < NK0; ++kk)
#pragma unroll
      for (int rt = 0; rt < 2; ++rt)
#pragma unroll
        for (int ct = 0; ct < 4; ++ct)
          acc[rt][ct] = __builtin_amdgcn_mfma_f32_16x16x32_bf16(
              afr[kk][rt], wfr[kk][ct], acc[rt][ct], 0, 0, 0);
#pragma unroll
    for (int ct = 0; ct < 4; ++ct) {
      int col = col0 + ct * 16 + l15;
#pragma unroll
      for (int rt = 0; rt < 2; ++rt)
#pragma unroll
        for (int i = 0; i < 4; ++i) {
          int row_l = rt * 16 + kg * 4 + i;
          buf[row_l * MID_STRIDE + col] = bfbits(fmaxf(acc[rt][ct][i] + bv[ct], 0.0f));
        }
    }
  };

  auto consume = [&](int c, const unsigned short* buf) {
    const int r0 = c << 5;
    f32x4 acc[2][4];
#pragma unroll
    for (int rt = 0; rt < 2; ++rt)
#pragma unroll
      for (int ct = 0; ct < 4; ++ct) acc[rt][ct] = 0.0f;
#pragma unroll
    for (int kk = 0; kk < NK1; ++kk) {
      bf16x8 mfr[2];
#pragma unroll
      for (int rt = 0; rt < 2; ++rt)
        mfr[rt] = *reinterpret_cast<const bf16x8*>(
            buf + (rt * 16 + l15) * MID_STRIDE + kk * 32 + kg * 8);
#pragma unroll
      for (int rt = 0; rt < 2; ++rt)
#pragma unroll
        for (int ct = 0; ct < 4; ++ct)
          acc[rt][ct] = __builtin_amdgcn_mfma_f32_16x16x32_bf16(
              mfr[rt], wfr[kk][ct], acc[rt][ct], 0, 0, 0);
    }
#pragma unroll
    for (int ct = 0; ct < 4; ++ct) {
      int col = col0 + ct * 16 + l15;
#pragma unroll
      for (int rt = 0; rt < 2; ++rt)
#pragma unroll
        for (int i = 0; i < 4; ++i) {
          int row = r0 + rt * 16 + kg * 4 + i;
          if (row < Nrows) {
            float v = fmaxf(acc[rt][ct][i] + bv[ct], 0.0f);
            if (OUT_BF16)
              ((__hip_bfloat16*)Outp)[(size_t)row * D_H + col] = __float2bfloat16(v);
            else
              ((float*)Outp)[(size_t)row * D_H + col] = v;
          }
        }
    }
  };

  int c_pr = blockIdx.x;
  int c_co = blockIdx.x;
  int pb = 0;
  if (prod && c_pr < nch) produce(c_pr, midb[0]);
  __syncthreads();
  c_pr += gridDim.x;
  while (c_co < nch) {
    if (prod) {
      if (c_pr < nch) produce(c_pr, midb[pb ^ 1]);
    } else {
      consume(c_co, midb[pb]);
    }
    __syncthreads();
    pb ^= 1;
    c_pr += gridDim.x;
    c_co += gridDim.x;
  }
}

extern "C" void kernel_launch(void* const* d_in, const int* in_sizes, int n_in,
                              void* d_out, int out_size, void* d_ws, size_t ws_size,
                              hipStream_t stream) {
  const float* x = (const float*)d_in[0];
  const int* ei = (const int*)d_in[1];  // [2, E]: row0 = src, row1 = dst
  const float* eps_all = (const float*)d_in[2];
  const float* w0_l0 = (const float*)d_in[3];
  const float* b0_l0 = (const float*)d_in[4];
  const float* w1_l0 = (const float*)d_in[5];
  const float* b1_l0 = (const float*)d_in[6];
  const float* w0_rest = (const float*)d_in[7];
  const float* b0_rest = (const float*)d_in[8];
  const float* w1_rest = (const float*)d_in[9];
  const float* b1_rest = (const float*)d_in[10];

  const int N = in_sizes[0] / D_IN;  // 50000
  const int E = in_sizes[1] / 2;     // 800000
  const int NX = N * D_IN;           // x elements

  char* ws = (char*)d_ws;
  const size_t node_bf = (size_t)N * D_H * sizeof(unsigned short);  // 25.6 MB
  unsigned short* h = (unsigned short*)ws;                // layer outputs
  unsigned short* pre = (unsigned short*)(ws + node_bf);  // aggregate out
  unsigned short* xb = (unsigned short*)(ws + 2 * node_bf);  // x cast to bf16
  char* p = ws + 2 * node_bf + (size_t)NX * sizeof(unsigned short);
  __hip_bfloat16* wbf = (__hip_bfloat16*)p;
  p += 622592 * sizeof(__hip_bfloat16);
  int* deg = (int*)p;           // [N]
  int* cursor = deg + N;        // [N]
  int* row_start = cursor + N;  // [N]
  int* bsum = row_start + N;    // [64]
  int* csr = bsum + 64;         // [E]

  __hip_bfloat16* w0_l0_bf = wbf;
  __hip_bfloat16* w1_l0_bf = wbf + 32768;
  __hip_bfloat16* w0_rest_bf = wbf + 98304;
  __hip_bfloat16* w1_rest_bf = w0_rest_bf + 262144;

  conv_inputs<<<(NX + 622592 + 255) / 256, 256, 0, stream>>>(
      x, w0_l0, w1_l0, w0_rest, w1_rest, (__hip_bfloat16*)xb, wbf, NX);

  // CSR build
  const int nb = (N + 1023) / 1024;  // 49
  zero_ints<<<(2 * N + 255) / 256, 256, 0, stream>>>(deg, 2 * N);  // deg + cursor
  hist_kernel<<<8 * CSR_CHUNKS, 256, 0, stream>>>(ei, E, deg, N);
  block_sums<<<nb, 256, 0, stream>>>(deg, bsum, N);
  scan_bsums<<<1, 64, 0, stream>>>(bsum, nb);
  scan_apply<<<nb, 256, 0, stream>>>(deg, bsum, row_start, N);
  fill_kernel<<<8 * CSR_CHUNKS, 256, 0, stream>>>(ei, E, row_start, cursor, csr, N);

  const int mlpGrid = 256;  // one 8-wave block per CU
  const int aggBlocks = (N + 7) / 8;

  for (int layer = 0; layer < NLAYERS; ++layer) {
    const __hip_bfloat16* w0 =
        (layer == 0) ? w0_l0_bf : w0_rest_bf + (size_t)(layer - 1) * 65536;
    const float* b0 = (layer == 0) ? b0_l0 : b0_rest + (size_t)(layer - 1) * 256;
    const __hip_bfloat16* w1 =
        (layer == 0) ? w1_l0_bf : w1_rest_bf + (size_t)(layer - 1) * 65536;
    const float* b1 = (layer == 0) ? b1_l0 : b1_rest + (size_t)(layer - 1) * 256;

    if (layer == 0) {
      aggregate<D_IN><<<aggBlocks, 256, 0, stream>>>(xb, csr, row_start, deg,
                                                     eps_all, layer, pre, N);
      mlp_fused<D_IN, true><<<mlpGrid, 512, 0, stream>>>(pre, w0, b0, w1, b1, h, N);
    } else {
      aggregate<D_H><<<aggBlocks, 256, 0, stream>>>(h, csr, row_start, deg,
                                                    eps_all, layer, pre, N);
      if (layer == NLAYERS - 1)
        mlp_fused<D_H, false><<<mlpGrid, 512, 0, stream>>>(pre, w0, b0, w1, b1,
                                                           d_out, N);
      else
        mlp_fused<D_H, true><<<mlpGrid, 512, 0, stream>>>(pre, w0, b0, w1, b1, h, N);
    }
  }
}